// Round 14
// baseline (362.576 us; speedup 1.0000x reference)
//
#include <hip/hip_runtime.h>
#include <cstdint>
#include <cstddef>

#define L_LAYERS 3
#define H_HEADS 8
#define D_EMB 128
#define DKV 16
#define FF_DIM 512
#define B_BATCH 32
#define N_SEQ 512
#define F_INP 16
#define OUT_DIM 3
#define M_ROWS (B_BATCH * N_SEQ)   // 16384
#define QSCALE 0.3606737602222409f // 0.25 * log2(e): scores in log2 domain

typedef unsigned short ushort_t;
typedef unsigned int uint_t;
typedef __attribute__((ext_vector_type(8))) short short8;
typedef __attribute__((ext_vector_type(4))) float f32x4;
typedef __attribute__((ext_vector_type(16))) float f32x16;

__device__ inline ushort_t f2bf(float x) {   // RNE float->bf16
    union { float f; uint_t u; } v; v.f = x;
    uint_t r = v.u + 0x7fffu + ((v.u >> 16) & 1u);
    return (ushort_t)(r >> 16);
}

__device__ inline uint_t pack2bf_tr(float a, float b) {  // truncating pack: lo=a, hi=b
    union { float f; uint_t u; } ua, ub;
    ua.f = a; ub.f = b;
#if __has_builtin(__builtin_amdgcn_perm)
    return __builtin_amdgcn_perm(ub.u, ua.u, 0x07060302u);  // 1 VALU op, bit-identical
#else
    return (ua.u >> 16) | (ub.u & 0xffff0000u);
#endif
}

__device__ inline float exp2fast(float x) {   // raw v_exp_f32 (2^x)
#if __has_builtin(__builtin_amdgcn_exp2f)
    return __builtin_amdgcn_exp2f(x);
#else
    float r; __asm__("v_exp_f32 %0, %1" : "=v"(r) : "v"(x)); return r;
#endif
}

__device__ inline void gload16(const void* g, void* l) {
    __builtin_amdgcn_global_load_lds(
        (const __attribute__((address_space(1))) unsigned int*)g,
        (__attribute__((address_space(3))) unsigned int*)l, 16, 0, 0);
}

// Half-swap with PINNED semantics (R12's builtin-based version failed
// correctness; the builtin's operand/return convention was the one unverified
// link). This form is verified line-by-line against the fragment derivation:
//   ra = {lanes 0-31: b from lane+32 ; lanes 32-63: own a}
//   rb = {lanes 0-31: own b         ; lanes 32-63: a from lane-32}
__device__ inline void plswap(uint_t a, uint_t b, uint_t& ra, uint_t& rb) {
    const uint_t sb = (uint_t)__shfl_xor((int)b, 32);
    const uint_t sa = (uint_t)__shfl_xor((int)a, 32);
    const bool lo = (threadIdx.x & 32) == 0;
    ra = lo ? sb : a;
    rb = lo ? b : sa;
}

// ---------------- fused preprocessing v2 (R7 config) ----------------
#define PM_BLK 2048    // x16 chunks each
#define RQ_BLK 576
#define TW_BLK 192
#define T1_BLK 768
#define T2_BLK 768
#define PB_BLK 16
#define EM_BLK 1024    // x8 row-pairs each
__global__ __launch_bounds__(256) void preproc_kernel(
        const int* __restrict__ mask, unsigned long long* __restrict__ pm,
        const float* __restrict__ Wq, const float* __restrict__ Wk,
        const float* __restrict__ Wv, ushort_t* __restrict__ wqkvT,
        const float* __restrict__ Wout, ushort_t* __restrict__ woutT,
        const float* __restrict__ Wff1, ushort_t* __restrict__ wff1T,
        const float* __restrict__ Wff2, ushort_t* __restrict__ wff2T,
        float* __restrict__ pbsum,
        const float* __restrict__ x, const float* __restrict__ We,
        float* __restrict__ hf, ushort_t* __restrict__ hb) {
    int bx = blockIdx.x;
    const int tid = threadIdx.x;
    if (bx < PM_BLK) {
#pragma unroll 4
        for (int it = 0; it < 16; ++it) {
            const int gid = (bx * 16 + it) * 256 + tid;
            const int v = mask[gid];
            const unsigned long long bal = __ballot(v != 0);
            if ((tid & 63) == 0) pm[gid >> 6] = bal;
        }
        return;
    }
    bx -= PM_BLK;
    if (bx < RQ_BLK) {
        int idx = bx * 256 + tid;
        int d = idx & 127;
        int n = (idx >> 7) % 384;
        int l = idx / (384 * 128);
        int proj = n >> 7, hh = (n & 127) >> 4, kk = n & 15;
        const float* src = proj == 0 ? Wq : proj == 1 ? Wk : Wv;
        wqkvT[idx] = f2bf(src[((size_t)(l * 8 + hh) * 128 + d) * 16 + kk]);
        return;
    }
    bx -= RQ_BLK;
    if (bx < TW_BLK + T1_BLK + T2_BLK) {
        const float* src; ushort_t* dst; int R, C;
        if (bx < TW_BLK) { src = Wout; dst = woutT; R = 128; C = 128; }
        else if (bx < TW_BLK + T1_BLK) { src = Wff1; dst = wff1T; R = 128; C = 512; bx -= TW_BLK; }
        else { src = Wff2; dst = wff2T; R = 512; C = 128; bx -= TW_BLK + T1_BLK; }
        int idx = bx * 256 + tid;
        int b = idx / (R * C);
        int rem = idx - b * (R * C);
        int c = rem / R, r = rem - c * R;
        dst[idx] = f2bf(src[((size_t)b * R + r) * C + c]);
        return;
    }
    bx -= TW_BLK + T1_BLK + T2_BLK;
    if (bx < PB_BLK) {
        pbsum[bx * 256 + tid] = 0.f;
        return;
    }
    bx -= PB_BLK;
    {
        const int d = tid & 127;
#pragma unroll 2
        for (int it = 0; it < 8; ++it) {
            const int m = (bx * 8 + it) * 2 + (tid >> 7);
            const float* xr = x + (size_t)m * 16;
            float acc = 0.f;
#pragma unroll
            for (int k = 0; k < 16; k++) acc += xr[k] * We[k * 128 + d];
            acc = fmaxf(acc, 0.f);
            hf[(size_t)m * 128 + d] = acc;
            hb[(size_t)m * 128 + d] = f2bf(acc);
        }
    }
}

// ---------------- fused QKV-GEMM + flash attention v13b: zero-LDS P ----------------
// [R14: byte-identical resubmission of R13 — bench infra failed twice with no
//  kernel verdict ("container failed twice"), same signature as R9 which ran
//  clean on resubmit. Full fragment-algebra audit repeated; see journal.]
// Ps LDS round-trip deleted; PV = 2x mfma_32x32x16 with ones-columns of Vt
// producing the softmax denominator inside the same MFMAs; plswap pinned to
// the verified shfl_xor construction.
__global__ __launch_bounds__(512, 4) void qkv_attn_kernel(
        const ushort_t* __restrict__ hb,    // [16384][128] bf16
        const ushort_t* __restrict__ WqkvT, // layer slice [384][128] bf16 B^T
        const uint_t* __restrict__ pm,      // packed mask
        ushort_t* __restrict__ Aout) {      // [16384][128] bf16
    __shared__ __align__(16) ushort_t sm[39168];   // 78.3 KB
    ushort_t* KF = sm;            // [16][512]
    ushort_t* Vt = sm + 8192;     // [32][520]; rows 16..31 = bf16 1.0
    ushort_t* Qs = sm + 24832;    // [512][16]
    ushort_t* Ws = sm + 33024;    // [48][128]

    const int tid = threadIdx.x;
    const int w = tid >> 6, L = tid & 63;
    const int lr = L & 15, lq = L >> 4;
    const int lane31 = L & 31, lhalf = L >> 5;
    const int bx = blockIdx.x;
    const int b = bx >> 3, h = bx & 7;

    for (int i = tid; i < 768; i += 512) {
        const int row = i >> 4, cg = i & 15;
        const int proj = row >> 4, kk = row & 15;
        gload16(WqkvT + (size_t)(proj * 128 + h * 16 + kk) * 128 + cg * 8, &Ws[i * 8]);
    }
    // ones-rows of Vt: B-operand cols 16..31 -> row-sum (denominator) columns
    for (int i = tid; i < 8320; i += 512) Vt[8320 + i] = (ushort_t)0x3F80;
    __syncthreads();

    const ushort_t* Ab = hb + (size_t)b * 512 * 128;
    for (int mc = 0; mc < 4; mc++) {
        f32x4 acc[3];
#pragma unroll
        for (int j = 0; j < 3; j++) acc[j] = (f32x4){0.f, 0.f, 0.f, 0.f};
#pragma unroll
        for (int k0 = 0; k0 < 128; k0 += 32) {
            short8 af = *(const short8*)(Ab + (size_t)(mc * 128 + w * 16 + lr) * 128 + k0 + lq * 8);
#pragma unroll
            for (int j = 0; j < 3; j++) {
                short8 bf = *(const short8*)&Ws[(j * 16 + lr) * 128 + k0 + lq * 8];
                acc[j] = __builtin_amdgcn_mfma_f32_16x16x32_bf16(af, bf, acc[j], 0, 0, 0);
            }
        }
        const int rbase = mc * 128 + w * 16 + lq * 4;
#pragma unroll
        for (int r = 0; r < 4; r++) {
            const int key = rbase + r;
            KF[(key >> 5) * 512 + ((lr >> 3) * 32 + (key & 31)) * 8 + (lr & 7)] = f2bf(acc[1][r]);
            Vt[lr * 520 + key] = f2bf(acc[2][r]);
            Qs[(key) * 16 + lr] = f2bf(acc[0][r] * QSCALE);
        }
    }
    __syncthreads();   // KF/Vt/Qs complete (nothing overwrites them afterwards)

    // q-fragments to registers (Qs stays valid; no further barrier needed)
    const short8 qf0 = *(const short8*)&Qs[(w * 32 + lane31) * 16 + lhalf * 8];
    const short8 qf1 = *(const short8*)&Qs[(256 + w * 32 + lane31) * 16 + lhalf * 8];

    const f32x16 zero16 = (f32x16)(0.f);

    for (int qloop = 0; qloop < 2; ++qloop) {
        const int q0g = qloop * 256 + w * 32;
        const short8 qf = qloop ? qf1 : qf0;
        const uint_t* pmr = pm + (size_t)(b * 512 + q0g + lane31) * 16;
        const uint4 mwa = *(const uint4*)(pmr);
        const uint4 mwb = *(const uint4*)(pmr + 4);
        const uint4 mwc = *(const uint4*)(pmr + 8);
        const uint4 mwd = *(const uint4*)(pmr + 12);
        const uint_t mw[16] = {mwa.x, mwa.y, mwa.z, mwa.w, mwb.x, mwb.y, mwb.z, mwb.w,
                               mwc.x, mwc.y, mwc.z, mwc.w, mwd.x, mwd.y, mwd.z, mwd.w};

        f32x16 oacc = zero16;

#pragma unroll
        for (int t = 0; t < 16; ++t) {
            short8 kf = *(const short8*)&KF[t * 512 + L * 8];
            f32x16 s = __builtin_amdgcn_mfma_f32_32x32x16_bf16(kf, qf, zero16, 0, 0, 0);
            const uint_t word = mw[t];
#pragma unroll
            for (int r = 0; r < 16; r++) {
                const int keyl = (r & 3) + 8 * (r >> 2) + 4 * lhalf;
                const float e = exp2fast(s[r]);
                s[r] = (word & (1u << keyl)) ? e : 0.f;
            }
            // pack: U[2g]=keys(8g+4lh+0,1), U[2g+1]=keys(8g+4lh+2,3)
            uint_t u0 = pack2bf_tr(s[0], s[1]),  u1 = pack2bf_tr(s[2], s[3]);
            uint_t u2 = pack2bf_tr(s[4], s[5]),  u3 = pack2bf_tr(s[6], s[7]);
            uint_t u4 = pack2bf_tr(s[8], s[9]),  u5 = pack2bf_tr(s[10], s[11]);
            uint_t u6 = pack2bf_tr(s[12], s[13]), u7 = pack2bf_tr(s[14], s[15]);

            // sub-tile 0 (keys t*32 + 0..15):
            // low lanes need words {own u0, own u1, high u0, high u1}
            // high lanes need      {low u2, low u3, own u2, own u3}
            uint_t f0, f1, f2, f3;
            plswap(u2, u0, f2, f0);
            plswap(u3, u1, f3, f1);
            union { uint_t u[4]; short8 s8; } cv0;
            cv0.u[0] = f0; cv0.u[1] = f1; cv0.u[2] = f2; cv0.u[3] = f3;
            short8 vb0 = *(const short8*)&Vt[lane31 * 520 + t * 32 + lhalf * 8];
            oacc = __builtin_amdgcn_mfma_f32_32x32x16_bf16(cv0.s8, vb0, oacc, 0, 0, 0);

            // sub-tile 1 (keys t*32 + 16..31)
            uint_t g0, g1, g2, g3;
            plswap(u6, u4, g2, g0);
            plswap(u7, u5, g3, g1);
            union { uint_t u[4]; short8 s8; } cv1;
            cv1.u[0] = g0; cv1.u[1] = g1; cv1.u[2] = g2; cv1.u[3] = g3;
            short8 vb1 = *(const short8*)&Vt[lane31 * 520 + t * 32 + 16 + lhalf * 8];
            oacc = __builtin_amdgcn_mfma_f32_32x32x16_bf16(cv1.s8, vb1, oacc, 0, 0, 0);
        }

        // epilogue: C[row=q][col]: cols 0..15 = O[q][dk], col 16 = row-sum l[q]
#pragma unroll
        for (int r = 0; r < 16; r++) {
            const int qrow = (r & 3) + 8 * (r >> 2) + 4 * lhalf;
            const float lsum = __shfl(oacc[r], (L & 32) | 16);
            if (lane31 < 16)
                Aout[(size_t)(b * 512 + q0g + qrow) * 128 + h * 16 + lane31] = f2bf(oacc[r] / lsum);
        }
    }
}

// ---------------- fused layer tail v4: ping-pong double-buffered staging ----------------
// (exact R0/R3 config — measured-best)
__global__ __launch_bounds__(256, 2) void tail_kernel(
        const ushort_t* __restrict__ A,     // a16 [16384][128]
        const ushort_t* __restrict__ WoT,   // [128 n][128 k]
        const ushort_t* __restrict__ W1T,   // [512 n][128 k]
        const ushort_t* __restrict__ W2T,   // [128 n][512 k]
        const float* __restrict__ b1,
        const float* __restrict__ b2,
        float* __restrict__ hf, ushort_t* __restrict__ hb,
        float* __restrict__ pbsum, int accum) {
    __shared__ __align__(16) ushort_t sm[39424];   // 78.85 KB -> 2 blocks/CU
    ushort_t* AsA = sm;            // 1024  (32x32 chunk)
    ushort_t* AsB = sm + 1024;     // 1024
    ushort_t* BsA = sm + 2048;     // 8192  (up to 256x32 chunk)
    ushort_t* BsB = sm + 10240;    // 8192
    ushort_t* C1b = sm + 18432;    // 4352  (32x136)
    ushort_t* T   = sm + 22784;    // 16640 (32x520)

    const int tid = threadIdx.x;
    const int w = tid >> 6, l = tid & 63;
    const int lr = l & 15, lq = l >> 4;
    const int srow = (l >> 2);
    const int scol = (l & 3) * 8;
    const int m0 = blockIdx.x * 32;

    // ================ phase A: C1 = a16 @ WoT^T + h ================
    f32x4 c1a[2][2];
#pragma unroll
    for (int i = 0; i < 2; i++)
#pragma unroll
        for (int j = 0; j < 2; j++) c1a[i][j] = (f32x4){0.f, 0.f, 0.f, 0.f};
    // prologue: stage k0=0
    if (w < 2)
        gload16(A + (size_t)(m0 + w * 16 + srow) * 128 + scol, &AsA[(w * 16 + srow) * 32 + scol]);
#pragma unroll
    for (int it = 0; it < 2; it++)
        gload16(WoT + (size_t)(it * 64 + w * 16 + srow) * 128 + scol, &BsA[(it * 64 + w * 16 + srow) * 32 + scol]);
#pragma unroll
    for (int k0 = 0; k0 < 128; k0 += 32) {
        ushort_t* Ac = (k0 & 32) ? AsB : AsA;
        ushort_t* Bc = (k0 & 32) ? BsB : BsA;
        ushort_t* An = (k0 & 32) ? AsA : AsB;
        ushort_t* Bn = (k0 & 32) ? BsA : BsB;
        __syncthreads();   // chunk k0 staged; prior reads of An/Bn done
        if (k0 + 32 < 128) {
            if (w < 2)
                gload16(A + (size_t)(m0 + w * 16 + srow) * 128 + k0 + 32 + scol,
                        &An[(w * 16 + srow) * 32 + scol]);
#pragma unroll
            for (int it = 0; it < 2; it++)
                gload16(WoT + (size_t)(it * 64 + w * 16 + srow) * 128 + k0 + 32 + scol,
                        &Bn[(it * 64 + w * 16 + srow) * 32 + scol]);
        }
        short8 af[2], bfr[2];
#pragma unroll
        for (int i = 0; i < 2; i++) af[i] = *(const short8*)&Ac[(i * 16 + lr) * 32 + lq * 8];
#pragma unroll
        for (int j = 0; j < 2; j++) bfr[j] = *(const short8*)&Bc[(w * 32 + j * 16 + lr) * 32 + lq * 8];
#pragma unroll
        for (int i = 0; i < 2; i++)
#pragma unroll
            for (int j = 0; j < 2; j++)
                c1a[i][j] = __builtin_amdgcn_mfma_f32_16x16x32_bf16(af[i], bfr[j], c1a[i][j], 0, 0, 0);
    }
    // epilogue A: + residual h (fp32 regs + bf16 LDS)
    float c1[2][2][4];
#pragma unroll
    for (int i = 0; i < 2; i++)
#pragma unroll
        for (int r = 0; r < 4; r++) {
            const int row = i * 16 + lq * 4 + r;
#pragma unroll
            for (int j = 0; j < 2; j++) {
                const int n = w * 32 + j * 16 + lr;
                const float v = c1a[i][j][r] + hf[(size_t)(m0 + row) * 128 + n];
                c1[i][j][r] = v;
                C1b[row * 136 + n] = f2bf(v);
            }
        }

    // ================ phase B: T = relu(C1 @ W1T^T + b1), 2 n-halves x 4 k-chunks ================
#pragma unroll
    for (int it = 0; it < 4; it++)
        gload16(W1T + (size_t)(it * 64 + w * 16 + srow) * 128 + scol, &BsA[(it * 64 + w * 16 + srow) * 32 + scol]);
#pragma unroll
    for (int nc = 0; nc < 2; nc++) {
        f32x4 ta[2][4];
#pragma unroll
        for (int i = 0; i < 2; i++)
#pragma unroll
            for (int j = 0; j < 4; j++) ta[i][j] = (f32x4){0.f, 0.f, 0.f, 0.f};
#pragma unroll
        for (int k0i = 0; k0i < 4; k0i++) {
            const int c = nc * 4 + k0i;
            ushort_t* Bc = (c & 1) ? BsB : BsA;
            ushort_t* Bn = (c & 1) ? BsA : BsB;
            __syncthreads();   // chunk c staged; also orders C1b writes (first iter)
            if (c + 1 < 8) {
                const int nc2 = (c + 1) >> 2, k02 = ((c + 1) & 3) * 32;
#pragma unroll
                for (int it = 0; it < 4; it++)
                    gload16(W1T + (size_t)(nc2 * 256 + it * 64 + w * 16 + srow) * 128 + k02 + scol,
                            &Bn[(it * 64 + w * 16 + srow) * 32 + scol]);
            }
            short8 af[2], bfr[4];
#pragma unroll
            for (int i = 0; i < 2; i++)
                af[i] = *(const short8*)&C1b[(i * 16 + lr) * 136 + k0i * 32 + lq * 8];
#pragma unroll
            for (int j = 0; j < 4; j++)
                bfr[j] = *(const short8*)&Bc[(w * 64 + j * 16 + lr) * 32 + lq * 8];
#pragma unroll
            for (int i = 0; i < 2; i++)
#pragma unroll
                for (int j = 0; j < 4; j++)
                    ta[i][j] = __builtin_amdgcn_mfma_f32_16x16x32_bf16(af[i], bfr[j], ta[i][j], 0, 0, 0);
        }
        // epilogue nc: +b1, relu -> T (distinct region; staging for next chunk flies concurrently)
#pragma unroll
        for (int j = 0; j < 4; j++) {
            const int n = nc * 256 + w * 64 + j * 16 + lr;
            const float bv = b1[n];
#pragma unroll
            for (int i = 0; i < 2; i++)
#pragma unroll
                for (int r = 0; r < 4; r++) {
                    const int row = i * 16 + lq * 4 + r;
                    T[row * 520 + n] = f2bf(fmaxf(ta[i][j][r] + bv, 0.f));
                }
        }
    }

    // ================ phase C: h' = C1 + T @ W2T^T + b2, 16 k-chunks ================
#pragma unroll
    for (int it = 0; it < 2; it++)
        gload16(W2T + (size_t)(it * 64 + w * 16 + srow) * 512 + scol, &BsA[(it * 64 + w * 16 + srow) * 32 + scol]);
    f32x4 oa[2][2];
#pragma unroll
    for (int i = 0; i < 2; i++)
#pragma unroll
        for (int j = 0; j < 2; j++) oa[i][j] = (f32x4){0.f, 0.f, 0.f, 0.f};
#pragma unroll
    for (int k0 = 0; k0 < 512; k0 += 32) {
        ushort_t* Bc = ((k0 >> 5) & 1) ? BsB : BsA;
        ushort_t* Bn = ((k0 >> 5) & 1) ? BsA : BsB;
        __syncthreads();   // chunk staged; T writes ordered (first iter)
        if (k0 + 32 < 512) {
#pragma unroll
            for (int it = 0; it < 2; it++)
                gload16(W2T + (size_t)(it * 64 + w * 16 + srow) * 512 + k0 + 32 + scol,
                        &Bn[(it * 64 + w * 16 + srow) * 32 + scol]);
        }
        short8 af[2], bfr[2];
#pragma unroll
        for (int i = 0; i < 2; i++)
            af[i] = *(const short8*)&T[(i * 16 + lr) * 520 + k0 + lq * 8];
#pragma unroll
        for (int j = 0; j < 2; j++)
            bfr[j] = *(const short8*)&Bc[(w * 32 + j * 16 + lr) * 32 + lq * 8];
#pragma unroll
        for (int i = 0; i < 2; i++)
#pragma unroll
            for (int j = 0; j < 2; j++)
                oa[i][j] = __builtin_amdgcn_mfma_f32_16x16x32_bf16(af[i], bfr[j], oa[i][j], 0, 0, 0);
    }
    // epilogue C: + b2 + C1 -> global fp32 + bf16 (+ pooled-sum atomics on last layer)
#pragma unroll
    for (int j = 0; j < 2; j++) {
        const int n = w * 32 + j * 16 + lr;
        const float bv = b2[n];
        float psum = 0.f;
#pragma unroll
        for (int i = 0; i < 2; i++)
#pragma unroll
            for (int r = 0; r < 4; r++) {
                const int row = i * 16 + lq * 4 + r;
                const float v = oa[i][j][r] + bv + c1[i][j][r];
                psum += v;
                hf[(size_t)(m0 + row) * 128 + n] = v;
                hb[(size_t)(m0 + row) * 128 + n] = f2bf(v);
            }
        if (accum) {
            psum += __shfl_xor(psum, 16);
            psum += __shfl_xor(psum, 32);
            if (lq == 0) atomicAdd(&pbsum[(m0 >> 9) * 128 + n], psum);
        }
    }
}

// ------------- readout: 512 blocks, 32 rows each (unchanged) -------------
__global__ __launch_bounds__(256) void readout_kernel(const float* __restrict__ h,
                                                      const float* __restrict__ pbsum,
                                                      const float* __restrict__ Wp,
                                                      const float* __restrict__ Wr,
                                                      const float* __restrict__ br,
                                                      float* __restrict__ out) {
    const int u = blockIdx.x;
    const int b = u >> 4;
    const int m0 = u * 32;
    const int t = threadIdx.x;
    __shared__ float pooled[128];
    __shared__ float rp[128];
    __shared__ float pb3[3];
    if (t < 128) pooled[t] = pbsum[b * 128 + t] * (1.0f / 512.0f);
    __syncthreads();
    if (t < 128) {
        float a = 0.f;
        for (int dd = 0; dd < 128; dd++) a += pooled[dd] * Wp[dd * 128 + t];
        rp[t] = fmaxf(a, 0.f);
    }
    __syncthreads();
    if (t < OUT_DIM) {
        float a = br[t];
        for (int j = 0; j < 128; j++) a += rp[j] * Wr[j * 3 + t];
        pb3[t] = a;
    }
    __syncthreads();
    const int j = t & 7;
    const int row = m0 + (t >> 3);
    const float* hr = h + (size_t)row * 128 + j * 16;
    float a0 = 0.f, a1 = 0.f, a2o = 0.f;
#pragma unroll
    for (int dd = 0; dd < 16; dd++) {
        const float v = fmaxf(hr[dd], 0.f);
        const float* wr = Wr + (size_t)(128 + j * 16 + dd) * 3;
        a0 += v * wr[0]; a1 += v * wr[1]; a2o += v * wr[2];
    }
#pragma unroll
    for (int off = 4; off; off >>= 1) {
        a0 += __shfl_down(a0, off, 8);
        a1 += __shfl_down(a1, off, 8);
        a2o += __shfl_down(a2o, off, 8);
    }
    if (j == 0) {
        out[(size_t)row * 3 + 0] = a0 + pb3[0];
        out[(size_t)row * 3 + 1] = a1 + pb3[1];
        out[(size_t)row * 3 + 2] = a2o + pb3[2];
    }
}

extern "C" void kernel_launch(void* const* d_in, const int* in_sizes, int n_in,
                              void* d_out, int out_size, void* d_ws, size_t ws_size,
                              hipStream_t stream) {
    const float* x    = (const float*)d_in[0];
    const int*   mask = (const int*)d_in[1];
    const float* We   = (const float*)d_in[2];
    const float* Wq   = (const float*)d_in[3];
    const float* Wk   = (const float*)d_in[4];
    const float* Wv   = (const float*)d_in[5];
    const float* Wout = (const float*)d_in[6];
    const float* Wff1 = (const float*)d_in[7];
    const float* bff1 = (const float*)d_in[8];
    const float* Wff2 = (const float*)d_in[9];
    const float* bff2 = (const float*)d_in[10];
    const float* Wp   = (const float*)d_in[11];
    const float* Wr   = (const float*)d_in[12];
    const float* br   = (const float*)d_in[13];
    float* out = (float*)d_out;

    char* ws = (char*)d_ws;
    unsigned long long* pm64 = (unsigned long long*)(ws + 0);        // 1 MiB
    const uint_t* pm32       = (const uint_t*)(ws + 0);
    ushort_t* wqkvT = (ushort_t*)(ws + 1048576);
    ushort_t* woutT = (ushort_t*)(ws + 1343488);
    ushort_t* wff1T = (ushort_t*)(ws + 1441792);
    ushort_t* wff2T = (ushort_t*)(ws + 1835008);
    float*    pbsum = (float*)(ws + 2228224);                        // 16 KiB pooled sums
    float*    hbuf  = (float*)(ws + 4194304);                        // 8 MiB fp32 residual
    ushort_t* hb16  = (ushort_t*)(ws + 12582912);                    // 4 MiB bf16 mirror
    ushort_t* a16   = (ushort_t*)(ws + 41943040);                    // 4 MiB attn out

    preproc_kernel<<<PM_BLK + RQ_BLK + TW_BLK + T1_BLK + T2_BLK + PB_BLK + EM_BLK, 256, 0, stream>>>(
        mask, pm64, Wq, Wk, Wv, wqkvT, Wout, woutT, Wff1, wff1T, Wff2, wff2T,
        pbsum, x, We, hbuf, hb16);

    for (int l = 0; l < L_LAYERS; l++) {
        qkv_attn_kernel<<<256, 512, 0, stream>>>(
            hb16, wqkvT + (size_t)l * 384 * 128, pm32, a16);
        tail_kernel<<<M_ROWS / 32, 256, 0, stream>>>(
            a16, woutT + (size_t)l * 128 * 128, wff1T + (size_t)l * 512 * 128,
            wff2T + (size_t)l * 128 * 512, bff1 + l * 512, bff2 + l * 128,
            hbuf, hb16, pbsum, (l == L_LAYERS - 1) ? 1 : 0);
    }

    readout_kernel<<<512, 256, 0, stream>>>(hbuf, pbsum, Wp, Wr, br, out);
}

// Round 15
// 362.239 us; speedup vs baseline: 1.0009x; 1.0009x over previous
//
#include <hip/hip_runtime.h>
#include <cstdint>
#include <cstddef>

#define L_LAYERS 3
#define H_HEADS 8
#define D_EMB 128
#define DKV 16
#define FF_DIM 512
#define B_BATCH 32
#define N_SEQ 512
#define F_INP 16
#define OUT_DIM 3
#define M_ROWS (B_BATCH * N_SEQ)   // 16384
#define QSCALE 0.3606737602222409f // 0.25 * log2(e): scores in log2 domain

typedef unsigned short ushort_t;
typedef unsigned int uint_t;
typedef __attribute__((ext_vector_type(8))) short short8;
typedef __attribute__((ext_vector_type(4))) float f32x4;
typedef __attribute__((ext_vector_type(16))) float f32x16;
typedef __attribute__((ext_vector_type(4))) uint_t uint4v;

__device__ inline ushort_t f2bf(float x) {   // RNE float->bf16
    union { float f; uint_t u; } v; v.f = x;
    uint_t r = v.u + 0x7fffu + ((v.u >> 16) & 1u);
    return (ushort_t)(r >> 16);
}

__device__ inline uint_t pack2bf_tr(float a, float b) {  // truncating pack: lo=a, hi=b
    union { float f; uint_t u; } ua, ub;
    ua.f = a; ub.f = b;
#if __has_builtin(__builtin_amdgcn_perm)
    return __builtin_amdgcn_perm(ub.u, ua.u, 0x07060302u);  // 1 VALU op, bit-identical
#else
    return (ua.u >> 16) | (ub.u & 0xffff0000u);
#endif
}

__device__ inline float exp2fast(float x) {   // raw v_exp_f32 (2^x)
#if __has_builtin(__builtin_amdgcn_exp2f)
    return __builtin_amdgcn_exp2f(x);
#else
    float r; __asm__("v_exp_f32 %0, %1" : "=v"(r) : "v"(x)); return r;
#endif
}

__device__ inline void gload16(const void* g, void* l) {
    __builtin_amdgcn_global_load_lds(
        (const __attribute__((address_space(1))) unsigned int*)g,
        (__attribute__((address_space(3))) unsigned int*)l, 16, 0, 0);
}

// Half-swap with PINNED semantics (proven correct in R14):
//   ra = {lanes 0-31: b from lane+32 ; lanes 32-63: own a}
//   rb = {lanes 0-31: own b         ; lanes 32-63: a from lane-32}
__device__ inline void plswap(uint_t a, uint_t b, uint_t& ra, uint_t& rb) {
    const uint_t sb = (uint_t)__shfl_xor((int)b, 32);
    const uint_t sa = (uint_t)__shfl_xor((int)a, 32);
    const bool lo = (threadIdx.x & 32) == 0;
    ra = lo ? sb : a;
    rb = lo ? b : sa;
}

// ---------------- fused preprocessing v2 (R7 config) ----------------
#define PM_BLK 2048    // x16 chunks each
#define RQ_BLK 576
#define TW_BLK 192
#define T1_BLK 768
#define T2_BLK 768
#define PB_BLK 16
#define EM_BLK 1024    // x8 row-pairs each
__global__ __launch_bounds__(256) void preproc_kernel(
        const int* __restrict__ mask, unsigned long long* __restrict__ pm,
        const float* __restrict__ Wq, const float* __restrict__ Wk,
        const float* __restrict__ Wv, ushort_t* __restrict__ wqkvT,
        const float* __restrict__ Wout, ushort_t* __restrict__ woutT,
        const float* __restrict__ Wff1, ushort_t* __restrict__ wff1T,
        const float* __restrict__ Wff2, ushort_t* __restrict__ wff2T,
        float* __restrict__ pbsum,
        const float* __restrict__ x, const float* __restrict__ We,
        float* __restrict__ hf, ushort_t* __restrict__ hb) {
    int bx = blockIdx.x;
    const int tid = threadIdx.x;
    if (bx < PM_BLK) {
#pragma unroll 4
        for (int it = 0; it < 16; ++it) {
            const int gid = (bx * 16 + it) * 256 + tid;
            const int v = mask[gid];
            const unsigned long long bal = __ballot(v != 0);
            if ((tid & 63) == 0) pm[gid >> 6] = bal;
        }
        return;
    }
    bx -= PM_BLK;
    if (bx < RQ_BLK) {
        int idx = bx * 256 + tid;
        int d = idx & 127;
        int n = (idx >> 7) % 384;
        int l = idx / (384 * 128);
        int proj = n >> 7, hh = (n & 127) >> 4, kk = n & 15;
        const float* src = proj == 0 ? Wq : proj == 1 ? Wk : Wv;
        wqkvT[idx] = f2bf(src[((size_t)(l * 8 + hh) * 128 + d) * 16 + kk]);
        return;
    }
    bx -= RQ_BLK;
    if (bx < TW_BLK + T1_BLK + T2_BLK) {
        const float* src; ushort_t* dst; int R, C;
        if (bx < TW_BLK) { src = Wout; dst = woutT; R = 128; C = 128; }
        else if (bx < TW_BLK + T1_BLK) { src = Wff1; dst = wff1T; R = 128; C = 512; bx -= TW_BLK; }
        else { src = Wff2; dst = wff2T; R = 512; C = 128; bx -= TW_BLK + T1_BLK; }
        int idx = bx * 256 + tid;
        int b = idx / (R * C);
        int rem = idx - b * (R * C);
        int c = rem / R, r = rem - c * R;
        dst[idx] = f2bf(src[((size_t)b * R + r) * C + c]);
        return;
    }
    bx -= TW_BLK + T1_BLK + T2_BLK;
    if (bx < PB_BLK) {
        pbsum[bx * 256 + tid] = 0.f;
        return;
    }
    bx -= PB_BLK;
    {
        const int d = tid & 127;
#pragma unroll 2
        for (int it = 0; it < 8; ++it) {
            const int m = (bx * 8 + it) * 2 + (tid >> 7);
            const float* xr = x + (size_t)m * 16;
            float acc = 0.f;
#pragma unroll
            for (int k = 0; k < 16; k++) acc += xr[k] * We[k * 128 + d];
            acc = fmaxf(acc, 0.f);
            hf[(size_t)m * 128 + d] = acc;
            hb[(size_t)m * 128 + d] = f2bf(acc);
        }
    }
}

// ---------------- fused QKV-GEMM + flash attention v13c: zero-LDS P, no-spill ----------------
// v13c = R14's correctness-PROVEN v13b with the scratch spill removed: the
// P-fragment type-pun unions (address-taken -> allocated in scratch; R14
// counters: FETCH 104.6MB / WRITE 88MB per dispatch = spill round-trips)
// are replaced by ext-vector uint4v + __builtin_bit_cast — pure register
// reinterpretation. No other change.
__global__ __launch_bounds__(512, 4) void qkv_attn_kernel(
        const ushort_t* __restrict__ hb,    // [16384][128] bf16
        const ushort_t* __restrict__ WqkvT, // layer slice [384][128] bf16 B^T
        const uint_t* __restrict__ pm,      // packed mask
        ushort_t* __restrict__ Aout) {      // [16384][128] bf16
    __shared__ __align__(16) ushort_t sm[39168];   // 78.3 KB
    ushort_t* KF = sm;            // [16][512]
    ushort_t* Vt = sm + 8192;     // [32][520]; rows 16..31 = bf16 1.0
    ushort_t* Qs = sm + 24832;    // [512][16]
    ushort_t* Ws = sm + 33024;    // [48][128]

    const int tid = threadIdx.x;
    const int w = tid >> 6, L = tid & 63;
    const int lr = L & 15, lq = L >> 4;
    const int lane31 = L & 31, lhalf = L >> 5;
    const int bx = blockIdx.x;
    const int b = bx >> 3, h = bx & 7;

    for (int i = tid; i < 768; i += 512) {
        const int row = i >> 4, cg = i & 15;
        const int proj = row >> 4, kk = row & 15;
        gload16(WqkvT + (size_t)(proj * 128 + h * 16 + kk) * 128 + cg * 8, &Ws[i * 8]);
    }
    // ones-rows of Vt: B-operand cols 16..31 -> row-sum (denominator) columns
    for (int i = tid; i < 8320; i += 512) Vt[8320 + i] = (ushort_t)0x3F80;
    __syncthreads();

    const ushort_t* Ab = hb + (size_t)b * 512 * 128;
    for (int mc = 0; mc < 4; mc++) {
        f32x4 acc[3];
#pragma unroll
        for (int j = 0; j < 3; j++) acc[j] = (f32x4){0.f, 0.f, 0.f, 0.f};
#pragma unroll
        for (int k0 = 0; k0 < 128; k0 += 32) {
            short8 af = *(const short8*)(Ab + (size_t)(mc * 128 + w * 16 + lr) * 128 + k0 + lq * 8);
#pragma unroll
            for (int j = 0; j < 3; j++) {
                short8 bf = *(const short8*)&Ws[(j * 16 + lr) * 128 + k0 + lq * 8];
                acc[j] = __builtin_amdgcn_mfma_f32_16x16x32_bf16(af, bf, acc[j], 0, 0, 0);
            }
        }
        const int rbase = mc * 128 + w * 16 + lq * 4;
#pragma unroll
        for (int r = 0; r < 4; r++) {
            const int key = rbase + r;
            KF[(key >> 5) * 512 + ((lr >> 3) * 32 + (key & 31)) * 8 + (lr & 7)] = f2bf(acc[1][r]);
            Vt[lr * 520 + key] = f2bf(acc[2][r]);
            Qs[(key) * 16 + lr] = f2bf(acc[0][r] * QSCALE);
        }
    }
    __syncthreads();   // KF/Vt/Qs complete (nothing overwrites them afterwards)

    // q-fragments to registers (Qs stays valid; no further barrier needed)
    const short8 qf0 = *(const short8*)&Qs[(w * 32 + lane31) * 16 + lhalf * 8];
    const short8 qf1 = *(const short8*)&Qs[(256 + w * 32 + lane31) * 16 + lhalf * 8];

    const f32x16 zero16 = (f32x16)(0.f);

    for (int qloop = 0; qloop < 2; ++qloop) {
        const int q0g = qloop * 256 + w * 32;
        const short8 qf = qloop ? qf1 : qf0;
        const uint_t* pmr = pm + (size_t)(b * 512 + q0g + lane31) * 16;
        const uint4 mwa = *(const uint4*)(pmr);
        const uint4 mwb = *(const uint4*)(pmr + 4);
        const uint4 mwc = *(const uint4*)(pmr + 8);
        const uint4 mwd = *(const uint4*)(pmr + 12);
        const uint_t mw[16] = {mwa.x, mwa.y, mwa.z, mwa.w, mwb.x, mwb.y, mwb.z, mwb.w,
                               mwc.x, mwc.y, mwc.z, mwc.w, mwd.x, mwd.y, mwd.z, mwd.w};

        f32x16 oacc = zero16;

#pragma unroll
        for (int t = 0; t < 16; ++t) {
            short8 kf = *(const short8*)&KF[t * 512 + L * 8];
            f32x16 s = __builtin_amdgcn_mfma_f32_32x32x16_bf16(kf, qf, zero16, 0, 0, 0);
            const uint_t word = mw[t];
#pragma unroll
            for (int r = 0; r < 16; r++) {
                const int keyl = (r & 3) + 8 * (r >> 2) + 4 * lhalf;
                const float e = exp2fast(s[r]);
                s[r] = (word & (1u << keyl)) ? e : 0.f;
            }
            // pack: U[2g]=keys(8g+4lh+0,1), U[2g+1]=keys(8g+4lh+2,3)
            uint_t u0 = pack2bf_tr(s[0], s[1]),  u1 = pack2bf_tr(s[2], s[3]);
            uint_t u2 = pack2bf_tr(s[4], s[5]),  u3 = pack2bf_tr(s[6], s[7]);
            uint_t u4 = pack2bf_tr(s[8], s[9]),  u5 = pack2bf_tr(s[10], s[11]);
            uint_t u6 = pack2bf_tr(s[12], s[13]), u7 = pack2bf_tr(s[14], s[15]);

            // sub-tile 0 (keys t*32 + 0..15):
            // low lanes need words {own u0, own u1, high u0, high u1}
            // high lanes need      {low u2, low u3, own u2, own u3}
            uint_t f0, f1, f2, f3;
            plswap(u2, u0, f2, f0);
            plswap(u3, u1, f3, f1);
            uint4v cv0; cv0[0] = f0; cv0[1] = f1; cv0[2] = f2; cv0[3] = f3;
            short8 pa0 = __builtin_bit_cast(short8, cv0);
            short8 vb0 = *(const short8*)&Vt[lane31 * 520 + t * 32 + lhalf * 8];
            oacc = __builtin_amdgcn_mfma_f32_32x32x16_bf16(pa0, vb0, oacc, 0, 0, 0);

            // sub-tile 1 (keys t*32 + 16..31)
            uint_t g0, g1, g2, g3;
            plswap(u6, u4, g2, g0);
            plswap(u7, u5, g3, g1);
            uint4v cv1; cv1[0] = g0; cv1[1] = g1; cv1[2] = g2; cv1[3] = g3;
            short8 pa1 = __builtin_bit_cast(short8, cv1);
            short8 vb1 = *(const short8*)&Vt[lane31 * 520 + t * 32 + 16 + lhalf * 8];
            oacc = __builtin_amdgcn_mfma_f32_32x32x16_bf16(pa1, vb1, oacc, 0, 0, 0);
        }

        // epilogue: C[row=q][col]: cols 0..15 = O[q][dk], col 16 = row-sum l[q]
#pragma unroll
        for (int r = 0; r < 16; r++) {
            const int qrow = (r & 3) + 8 * (r >> 2) + 4 * lhalf;
            const float lsum = __shfl(oacc[r], (L & 32) | 16);
            if (lane31 < 16)
                Aout[(size_t)(b * 512 + q0g + qrow) * 128 + h * 16 + lane31] = f2bf(oacc[r] / lsum);
        }
    }
}

// ---------------- fused layer tail v4: ping-pong double-buffered staging ----------------
// (exact R0/R3 config — measured-best)
__global__ __launch_bounds__(256, 2) void tail_kernel(
        const ushort_t* __restrict__ A,     // a16 [16384][128]
        const ushort_t* __restrict__ WoT,   // [128 n][128 k]
        const ushort_t* __restrict__ W1T,   // [512 n][128 k]
        const ushort_t* __restrict__ W2T,   // [128 n][512 k]
        const float* __restrict__ b1,
        const float* __restrict__ b2,
        float* __restrict__ hf, ushort_t* __restrict__ hb,
        float* __restrict__ pbsum, int accum) {
    __shared__ __align__(16) ushort_t sm[39424];   // 78.85 KB -> 2 blocks/CU
    ushort_t* AsA = sm;            // 1024  (32x32 chunk)
    ushort_t* AsB = sm + 1024;     // 1024
    ushort_t* BsA = sm + 2048;     // 8192  (up to 256x32 chunk)
    ushort_t* BsB = sm + 10240;    // 8192
    ushort_t* C1b = sm + 18432;    // 4352  (32x136)
    ushort_t* T   = sm + 22784;    // 16640 (32x520)

    const int tid = threadIdx.x;
    const int w = tid >> 6, l = tid & 63;
    const int lr = l & 15, lq = l >> 4;
    const int srow = (l >> 2);
    const int scol = (l & 3) * 8;
    const int m0 = blockIdx.x * 32;

    // ================ phase A: C1 = a16 @ WoT^T + h ================
    f32x4 c1a[2][2];
#pragma unroll
    for (int i = 0; i < 2; i++)
#pragma unroll
        for (int j = 0; j < 2; j++) c1a[i][j] = (f32x4){0.f, 0.f, 0.f, 0.f};
    // prologue: stage k0=0
    if (w < 2)
        gload16(A + (size_t)(m0 + w * 16 + srow) * 128 + scol, &AsA[(w * 16 + srow) * 32 + scol]);
#pragma unroll
    for (int it = 0; it < 2; it++)
        gload16(WoT + (size_t)(it * 64 + w * 16 + srow) * 128 + scol, &BsA[(it * 64 + w * 16 + srow) * 32 + scol]);
#pragma unroll
    for (int k0 = 0; k0 < 128; k0 += 32) {
        ushort_t* Ac = (k0 & 32) ? AsB : AsA;
        ushort_t* Bc = (k0 & 32) ? BsB : BsA;
        ushort_t* An = (k0 & 32) ? AsA : AsB;
        ushort_t* Bn = (k0 & 32) ? BsA : BsB;
        __syncthreads();   // chunk k0 staged; prior reads of An/Bn done
        if (k0 + 32 < 128) {
            if (w < 2)
                gload16(A + (size_t)(m0 + w * 16 + srow) * 128 + k0 + 32 + scol,
                        &An[(w * 16 + srow) * 32 + scol]);
#pragma unroll
            for (int it = 0; it < 2; it++)
                gload16(WoT + (size_t)(it * 64 + w * 16 + srow) * 128 + k0 + 32 + scol,
                        &Bn[(it * 64 + w * 16 + srow) * 32 + scol]);
        }
        short8 af[2], bfr[2];
#pragma unroll
        for (int i = 0; i < 2; i++) af[i] = *(const short8*)&Ac[(i * 16 + lr) * 32 + lq * 8];
#pragma unroll
        for (int j = 0; j < 2; j++) bfr[j] = *(const short8*)&Bc[(w * 32 + j * 16 + lr) * 32 + lq * 8];
#pragma unroll
        for (int i = 0; i < 2; i++)
#pragma unroll
            for (int j = 0; j < 2; j++)
                c1a[i][j] = __builtin_amdgcn_mfma_f32_16x16x32_bf16(af[i], bfr[j], c1a[i][j], 0, 0, 0);
    }
    // epilogue A: + residual h (fp32 regs + bf16 LDS)
    float c1[2][2][4];
#pragma unroll
    for (int i = 0; i < 2; i++)
#pragma unroll
        for (int r = 0; r < 4; r++) {
            const int row = i * 16 + lq * 4 + r;
#pragma unroll
            for (int j = 0; j < 2; j++) {
                const int n = w * 32 + j * 16 + lr;
                const float v = c1a[i][j][r] + hf[(size_t)(m0 + row) * 128 + n];
                c1[i][j][r] = v;
                C1b[row * 136 + n] = f2bf(v);
            }
        }

    // ================ phase B: T = relu(C1 @ W1T^T + b1), 2 n-halves x 4 k-chunks ================
#pragma unroll
    for (int it = 0; it < 4; it++)
        gload16(W1T + (size_t)(it * 64 + w * 16 + srow) * 128 + scol, &BsA[(it * 64 + w * 16 + srow) * 32 + scol]);
#pragma unroll
    for (int nc = 0; nc < 2; nc++) {
        f32x4 ta[2][4];
#pragma unroll
        for (int i = 0; i < 2; i++)
#pragma unroll
            for (int j = 0; j < 4; j++) ta[i][j] = (f32x4){0.f, 0.f, 0.f, 0.f};
#pragma unroll
        for (int k0i = 0; k0i < 4; k0i++) {
            const int c = nc * 4 + k0i;
            ushort_t* Bc = (c & 1) ? BsB : BsA;
            ushort_t* Bn = (c & 1) ? BsA : BsB;
            __syncthreads();   // chunk c staged; also orders C1b writes (first iter)
            if (c + 1 < 8) {
                const int nc2 = (c + 1) >> 2, k02 = ((c + 1) & 3) * 32;
#pragma unroll
                for (int it = 0; it < 4; it++)
                    gload16(W1T + (size_t)(nc2 * 256 + it * 64 + w * 16 + srow) * 128 + k02 + scol,
                            &Bn[(it * 64 + w * 16 + srow) * 32 + scol]);
            }
            short8 af[2], bfr[4];
#pragma unroll
            for (int i = 0; i < 2; i++)
                af[i] = *(const short8*)&C1b[(i * 16 + lr) * 136 + k0i * 32 + lq * 8];
#pragma unroll
            for (int j = 0; j < 4; j++)
                bfr[j] = *(const short8*)&Bc[(w * 64 + j * 16 + lr) * 32 + lq * 8];
#pragma unroll
            for (int i = 0; i < 2; i++)
#pragma unroll
                for (int j = 0; j < 4; j++)
                    ta[i][j] = __builtin_amdgcn_mfma_f32_16x16x32_bf16(af[i], bfr[j], ta[i][j], 0, 0, 0);
        }
        // epilogue nc: +b1, relu -> T (distinct region; staging for next chunk flies concurrently)
#pragma unroll
        for (int j = 0; j < 4; j++) {
            const int n = nc * 256 + w * 64 + j * 16 + lr;
            const float bv = b1[n];
#pragma unroll
            for (int i = 0; i < 2; i++)
#pragma unroll
                for (int r = 0; r < 4; r++) {
                    const int row = i * 16 + lq * 4 + r;
                    T[row * 520 + n] = f2bf(fmaxf(ta[i][j][r] + bv, 0.f));
                }
        }
    }

    // ================ phase C: h' = C1 + T @ W2T^T + b2, 16 k-chunks ================
#pragma unroll
    for (int it = 0; it < 2; it++)
        gload16(W2T + (size_t)(it * 64 + w * 16 + srow) * 512 + scol, &BsA[(it * 64 + w * 16 + srow) * 32 + scol]);
    f32x4 oa[2][2];
#pragma unroll
    for (int i = 0; i < 2; i++)
#pragma unroll
        for (int j = 0; j < 2; j++) oa[i][j] = (f32x4){0.f, 0.f, 0.f, 0.f};
#pragma unroll
    for (int k0 = 0; k0 < 512; k0 += 32) {
        ushort_t* Bc = ((k0 >> 5) & 1) ? BsB : BsA;
        ushort_t* Bn = ((k0 >> 5) & 1) ? BsA : BsB;
        __syncthreads();   // chunk staged; T writes ordered (first iter)
        if (k0 + 32 < 512) {
#pragma unroll
            for (int it = 0; it < 2; it++)
                gload16(W2T + (size_t)(it * 64 + w * 16 + srow) * 512 + k0 + 32 + scol,
                        &Bn[(it * 64 + w * 16 + srow) * 32 + scol]);
        }
        short8 af[2], bfr[2];
#pragma unroll
        for (int i = 0; i < 2; i++)
            af[i] = *(const short8*)&T[(i * 16 + lr) * 520 + k0 + lq * 8];
#pragma unroll
        for (int j = 0; j < 2; j++)
            bfr[j] = *(const short8*)&Bc[(w * 32 + j * 16 + lr) * 32 + lq * 8];
#pragma unroll
        for (int i = 0; i < 2; i++)
#pragma unroll
            for (int j = 0; j < 2; j++)
                oa[i][j] = __builtin_amdgcn_mfma_f32_16x16x32_bf16(af[i], bfr[j], oa[i][j], 0, 0, 0);
    }
    // epilogue C: + b2 + C1 -> global fp32 + bf16 (+ pooled-sum atomics on last layer)
#pragma unroll
    for (int j = 0; j < 2; j++) {
        const int n = w * 32 + j * 16 + lr;
        const float bv = b2[n];
        float psum = 0.f;
#pragma unroll
        for (int i = 0; i < 2; i++)
#pragma unroll
            for (int r = 0; r < 4; r++) {
                const int row = i * 16 + lq * 4 + r;
                const float v = oa[i][j][r] + bv + c1[i][j][r];
                psum += v;
                hf[(size_t)(m0 + row) * 128 + n] = v;
                hb[(size_t)(m0 + row) * 128 + n] = f2bf(v);
            }
        if (accum) {
            psum += __shfl_xor(psum, 16);
            psum += __shfl_xor(psum, 32);
            if (lq == 0) atomicAdd(&pbsum[(m0 >> 9) * 128 + n], psum);
        }
    }
}

// ------------- readout: 512 blocks, 32 rows each (unchanged) -------------
__global__ __launch_bounds__(256) void readout_kernel(const float* __restrict__ h,
                                                      const float* __restrict__ pbsum,
                                                      const float* __restrict__ Wp,
                                                      const float* __restrict__ Wr,
                                                      const float* __restrict__ br,
                                                      float* __restrict__ out) {
    const int u = blockIdx.x;
    const int b = u >> 4;
    const int m0 = u * 32;
    const int t = threadIdx.x;
    __shared__ float pooled[128];
    __shared__ float rp[128];
    __shared__ float pb3[3];
    if (t < 128) pooled[t] = pbsum[b * 128 + t] * (1.0f / 512.0f);
    __syncthreads();
    if (t < 128) {
        float a = 0.f;
        for (int dd = 0; dd < 128; dd++) a += pooled[dd] * Wp[dd * 128 + t];
        rp[t] = fmaxf(a, 0.f);
    }
    __syncthreads();
    if (t < OUT_DIM) {
        float a = br[t];
        for (int j = 0; j < 128; j++) a += rp[j] * Wr[j * 3 + t];
        pb3[t] = a;
    }
    __syncthreads();
    const int j = t & 7;
    const int row = m0 + (t >> 3);
    const float* hr = h + (size_t)row * 128 + j * 16;
    float a0 = 0.f, a1 = 0.f, a2o = 0.f;
#pragma unroll
    for (int dd = 0; dd < 16; dd++) {
        const float v = fmaxf(hr[dd], 0.f);
        const float* wr = Wr + (size_t)(128 + j * 16 + dd) * 3;
        a0 += v * wr[0]; a1 += v * wr[1]; a2o += v * wr[2];
    }
#pragma unroll
    for (int off = 4; off; off >>= 1) {
        a0 += __shfl_down(a0, off, 8);
        a1 += __shfl_down(a1, off, 8);
        a2o += __shfl_down(a2o, off, 8);
    }
    if (j == 0) {
        out[(size_t)row * 3 + 0] = a0 + pb3[0];
        out[(size_t)row * 3 + 1] = a1 + pb3[1];
        out[(size_t)row * 3 + 2] = a2o + pb3[2];
    }
}

extern "C" void kernel_launch(void* const* d_in, const int* in_sizes, int n_in,
                              void* d_out, int out_size, void* d_ws, size_t ws_size,
                              hipStream_t stream) {
    const float* x    = (const float*)d_in[0];
    const int*   mask = (const int*)d_in[1];
    const float* We   = (const float*)d_in[2];
    const float* Wq   = (const float*)d_in[3];
    const float* Wk   = (const float*)d_in[4];
    const float* Wv   = (const float*)d_in[5];
    const float* Wout = (const float*)d_in[6];
    const float* Wff1 = (const float*)d_in[7];
    const float* bff1 = (const float*)d_in[8];
    const float* Wff2 = (const float*)d_in[9];
    const float* bff2 = (const float*)d_in[10];
    const float* Wp   = (const float*)d_in[11];
    const float* Wr   = (const float*)d_in[12];
    const float* br   = (const float*)d_in[13];
    float* out = (float*)d_out;

    char* ws = (char*)d_ws;
    unsigned long long* pm64 = (unsigned long long*)(ws + 0);        // 1 MiB
    const uint_t* pm32       = (const uint_t*)(ws + 0);
    ushort_t* wqkvT = (ushort_t*)(ws + 1048576);
    ushort_t* woutT = (ushort_t*)(ws + 1343488);
    ushort_t* wff1T = (ushort_t*)(ws + 1441792);
    ushort_t* wff2T = (ushort_t*)(ws + 1835008);
    float*    pbsum = (float*)(ws + 2228224);                        // 16 KiB pooled sums
    float*    hbuf  = (float*)(ws + 4194304);                        // 8 MiB fp32 residual
    ushort_t* hb16  = (ushort_t*)(ws + 12582912);                    // 4 MiB bf16 mirror
    ushort_t* a16   = (ushort_t*)(ws + 41943040);                    // 4 MiB attn out

    preproc_kernel<<<PM_BLK + RQ_BLK + TW_BLK + T1_BLK + T2_BLK + PB_BLK + EM_BLK, 256, 0, stream>>>(
        mask, pm64, Wq, Wk, Wv, wqkvT, Wout, woutT, Wff1, wff1T, Wff2, wff2T,
        pbsum, x, We, hbuf, hb16);

    for (int l = 0; l < L_LAYERS; l++) {
        qkv_attn_kernel<<<256, 512, 0, stream>>>(
            hb16, wqkvT + (size_t)l * 384 * 128, pm32, a16);
        tail_kernel<<<M_ROWS / 32, 256, 0, stream>>>(
            a16, woutT + (size_t)l * 128 * 128, wff1T + (size_t)l * 512 * 128,
            wff2T + (size_t)l * 128 * 512, bff1 + l * 512, bff2 + l * 128,
            hbuf, hb16, pbsum, (l == L_LAYERS - 1) ? 1 : 0);
    }

    readout_kernel<<<512, 256, 0, stream>>>(hbuf, pbsum, Wp, Wr, br, out);
}

// Round 16
// 280.421 us; speedup vs baseline: 1.2930x; 1.2918x over previous
//
#include <hip/hip_runtime.h>
#include <cstdint>
#include <cstddef>

#define L_LAYERS 3
#define H_HEADS 8
#define D_EMB 128
#define DKV 16
#define FF_DIM 512
#define B_BATCH 32
#define N_SEQ 512
#define F_INP 16
#define OUT_DIM 3
#define M_ROWS (B_BATCH * N_SEQ)   // 16384
#define QSCALE 0.3606737602222409f // 0.25 * log2(e): scores in log2 domain

typedef unsigned short ushort_t;
typedef unsigned int uint_t;
typedef __attribute__((ext_vector_type(8))) short short8;
typedef __attribute__((ext_vector_type(4))) float f32x4;
typedef __attribute__((ext_vector_type(16))) float f32x16;
typedef __attribute__((ext_vector_type(4))) uint_t uint4v;

__device__ inline ushort_t f2bf(float x) {   // RNE float->bf16
    union { float f; uint_t u; } v; v.f = x;
    uint_t r = v.u + 0x7fffu + ((v.u >> 16) & 1u);
    return (ushort_t)(r >> 16);
}

__device__ inline uint_t pack2bf_tr(float a, float b) {  // truncating pack: lo=a, hi=b
    union { float f; uint_t u; } ua, ub;
    ua.f = a; ub.f = b;
#if __has_builtin(__builtin_amdgcn_perm)
    return __builtin_amdgcn_perm(ub.u, ua.u, 0x07060302u);  // 1 VALU op, bit-identical
#else
    return (ua.u >> 16) | (ub.u & 0xffff0000u);
#endif
}

__device__ inline float exp2fast(float x) {   // raw v_exp_f32 (2^x)
#if __has_builtin(__builtin_amdgcn_exp2f)
    return __builtin_amdgcn_exp2f(x);
#else
    float r; __asm__("v_exp_f32 %0, %1" : "=v"(r) : "v"(x)); return r;
#endif
}

__device__ inline void gload16(const void* g, void* l) {
    __builtin_amdgcn_global_load_lds(
        (const __attribute__((address_space(1))) unsigned int*)g,
        (__attribute__((address_space(3))) unsigned int*)l, 16, 0, 0);
}

// Half-swap with PINNED semantics (proven correct in R14):
//   ra = {lanes 0-31: b from lane+32 ; lanes 32-63: own a}
//   rb = {lanes 0-31: own b         ; lanes 32-63: a from lane-32}
__device__ inline void plswap(uint_t a, uint_t b, uint_t& ra, uint_t& rb) {
    const uint_t sb = (uint_t)__shfl_xor((int)b, 32);
    const uint_t sa = (uint_t)__shfl_xor((int)a, 32);
    const bool lo = (threadIdx.x & 32) == 0;
    ra = lo ? sb : a;
    rb = lo ? b : sa;
}

// ---------------- fused preprocessing v2 (R7 config) ----------------
#define PM_BLK 2048    // x16 chunks each
#define RQ_BLK 576
#define TW_BLK 192
#define T1_BLK 768
#define T2_BLK 768
#define PB_BLK 16
#define EM_BLK 1024    // x8 row-pairs each
__global__ __launch_bounds__(256) void preproc_kernel(
        const int* __restrict__ mask, unsigned long long* __restrict__ pm,
        const float* __restrict__ Wq, const float* __restrict__ Wk,
        const float* __restrict__ Wv, ushort_t* __restrict__ wqkvT,
        const float* __restrict__ Wout, ushort_t* __restrict__ woutT,
        const float* __restrict__ Wff1, ushort_t* __restrict__ wff1T,
        const float* __restrict__ Wff2, ushort_t* __restrict__ wff2T,
        float* __restrict__ pbsum,
        const float* __restrict__ x, const float* __restrict__ We,
        float* __restrict__ hf, ushort_t* __restrict__ hb) {
    int bx = blockIdx.x;
    const int tid = threadIdx.x;
    if (bx < PM_BLK) {
#pragma unroll 4
        for (int it = 0; it < 16; ++it) {
            const int gid = (bx * 16 + it) * 256 + tid;
            const int v = mask[gid];
            const unsigned long long bal = __ballot(v != 0);
            if ((tid & 63) == 0) pm[gid >> 6] = bal;
        }
        return;
    }
    bx -= PM_BLK;
    if (bx < RQ_BLK) {
        int idx = bx * 256 + tid;
        int d = idx & 127;
        int n = (idx >> 7) % 384;
        int l = idx / (384 * 128);
        int proj = n >> 7, hh = (n & 127) >> 4, kk = n & 15;
        const float* src = proj == 0 ? Wq : proj == 1 ? Wk : Wv;
        wqkvT[idx] = f2bf(src[((size_t)(l * 8 + hh) * 128 + d) * 16 + kk]);
        return;
    }
    bx -= RQ_BLK;
    if (bx < TW_BLK + T1_BLK + T2_BLK) {
        const float* src; ushort_t* dst; int R, C;
        if (bx < TW_BLK) { src = Wout; dst = woutT; R = 128; C = 128; }
        else if (bx < TW_BLK + T1_BLK) { src = Wff1; dst = wff1T; R = 128; C = 512; bx -= TW_BLK; }
        else { src = Wff2; dst = wff2T; R = 512; C = 128; bx -= TW_BLK + T1_BLK; }
        int idx = bx * 256 + tid;
        int b = idx / (R * C);
        int rem = idx - b * (R * C);
        int c = rem / R, r = rem - c * R;
        dst[idx] = f2bf(src[((size_t)b * R + r) * C + c]);
        return;
    }
    bx -= TW_BLK + T1_BLK + T2_BLK;
    if (bx < PB_BLK) {
        pbsum[bx * 256 + tid] = 0.f;
        return;
    }
    bx -= PB_BLK;
    {
        const int d = tid & 127;
#pragma unroll 2
        for (int it = 0; it < 8; ++it) {
            const int m = (bx * 8 + it) * 2 + (tid >> 7);
            const float* xr = x + (size_t)m * 16;
            float acc = 0.f;
#pragma unroll
            for (int k = 0; k < 16; k++) acc += xr[k] * We[k * 128 + d];
            acc = fmaxf(acc, 0.f);
            hf[(size_t)m * 128 + d] = acc;
            hb[(size_t)m * 128 + d] = f2bf(acc);
        }
    }
}

// ---------------- fused QKV-GEMM + flash attention v13d: zero-LDS P, unspilled ----------------
// v13d = correctness-proven v13 structure with the REAL spill fix: R14/R15
// counters showed VGPR_Count=64 + 104MB FETCH / 88MB WRITE per dispatch —
// the (512,4) launch bound capped the allocator at 64 VGPRs (live set ~100)
// and everything round-tripped through scratch; the bit_cast change (R15)
// was a codegen no-op. (512,2) raises the cap to 256 (R10 precedent:
// VGPR=128 at this bound). LDS 78.3 KB still allows 2 blocks/CU if the
// allocation lands <=128.
__global__ __launch_bounds__(512, 2) void qkv_attn_kernel(
        const ushort_t* __restrict__ hb,    // [16384][128] bf16
        const ushort_t* __restrict__ WqkvT, // layer slice [384][128] bf16 B^T
        const uint_t* __restrict__ pm,      // packed mask
        ushort_t* __restrict__ Aout) {      // [16384][128] bf16
    __shared__ __align__(16) ushort_t sm[39168];   // 78.3 KB
    ushort_t* KF = sm;            // [16][512]
    ushort_t* Vt = sm + 8192;     // [32][520]; rows 16..31 = bf16 1.0
    ushort_t* Qs = sm + 24832;    // [512][16]
    ushort_t* Ws = sm + 33024;    // [48][128]

    const int tid = threadIdx.x;
    const int w = tid >> 6, L = tid & 63;
    const int lr = L & 15, lq = L >> 4;
    const int lane31 = L & 31, lhalf = L >> 5;
    const int bx = blockIdx.x;
    const int b = bx >> 3, h = bx & 7;

    for (int i = tid; i < 768; i += 512) {
        const int row = i >> 4, cg = i & 15;
        const int proj = row >> 4, kk = row & 15;
        gload16(WqkvT + (size_t)(proj * 128 + h * 16 + kk) * 128 + cg * 8, &Ws[i * 8]);
    }
    // ones-rows of Vt: B-operand cols 16..31 -> row-sum (denominator) columns
    for (int i = tid; i < 8320; i += 512) Vt[8320 + i] = (ushort_t)0x3F80;
    __syncthreads();

    const ushort_t* Ab = hb + (size_t)b * 512 * 128;
    for (int mc = 0; mc < 4; mc++) {
        f32x4 acc[3];
#pragma unroll
        for (int j = 0; j < 3; j++) acc[j] = (f32x4){0.f, 0.f, 0.f, 0.f};
#pragma unroll
        for (int k0 = 0; k0 < 128; k0 += 32) {
            short8 af = *(const short8*)(Ab + (size_t)(mc * 128 + w * 16 + lr) * 128 + k0 + lq * 8);
#pragma unroll
            for (int j = 0; j < 3; j++) {
                short8 bf = *(const short8*)&Ws[(j * 16 + lr) * 128 + k0 + lq * 8];
                acc[j] = __builtin_amdgcn_mfma_f32_16x16x32_bf16(af, bf, acc[j], 0, 0, 0);
            }
        }
        const int rbase = mc * 128 + w * 16 + lq * 4;
#pragma unroll
        for (int r = 0; r < 4; r++) {
            const int key = rbase + r;
            KF[(key >> 5) * 512 + ((lr >> 3) * 32 + (key & 31)) * 8 + (lr & 7)] = f2bf(acc[1][r]);
            Vt[lr * 520 + key] = f2bf(acc[2][r]);
            Qs[(key) * 16 + lr] = f2bf(acc[0][r] * QSCALE);
        }
    }
    __syncthreads();   // KF/Vt/Qs complete (nothing overwrites them afterwards)

    // q-fragments to registers (Qs stays valid; no further barrier needed)
    const short8 qf0 = *(const short8*)&Qs[(w * 32 + lane31) * 16 + lhalf * 8];
    const short8 qf1 = *(const short8*)&Qs[(256 + w * 32 + lane31) * 16 + lhalf * 8];

    const f32x16 zero16 = (f32x16)(0.f);

    for (int qloop = 0; qloop < 2; ++qloop) {
        const int q0g = qloop * 256 + w * 32;
        const short8 qf = qloop ? qf1 : qf0;
        const uint_t* pmr = pm + (size_t)(b * 512 + q0g + lane31) * 16;
        const uint4 mwa = *(const uint4*)(pmr);
        const uint4 mwb = *(const uint4*)(pmr + 4);
        const uint4 mwc = *(const uint4*)(pmr + 8);
        const uint4 mwd = *(const uint4*)(pmr + 12);
        const uint_t mw[16] = {mwa.x, mwa.y, mwa.z, mwa.w, mwb.x, mwb.y, mwb.z, mwb.w,
                               mwc.x, mwc.y, mwc.z, mwc.w, mwd.x, mwd.y, mwd.z, mwd.w};

        f32x16 oacc = zero16;

#pragma unroll
        for (int t = 0; t < 16; ++t) {
            short8 kf = *(const short8*)&KF[t * 512 + L * 8];
            f32x16 s = __builtin_amdgcn_mfma_f32_32x32x16_bf16(kf, qf, zero16, 0, 0, 0);
            const uint_t word = mw[t];
#pragma unroll
            for (int r = 0; r < 16; r++) {
                const int keyl = (r & 3) + 8 * (r >> 2) + 4 * lhalf;
                const float e = exp2fast(s[r]);
                s[r] = (word & (1u << keyl)) ? e : 0.f;
            }
            // pack: U[2g]=keys(8g+4lh+0,1), U[2g+1]=keys(8g+4lh+2,3)
            uint_t u0 = pack2bf_tr(s[0], s[1]),  u1 = pack2bf_tr(s[2], s[3]);
            uint_t u2 = pack2bf_tr(s[4], s[5]),  u3 = pack2bf_tr(s[6], s[7]);
            uint_t u4 = pack2bf_tr(s[8], s[9]),  u5 = pack2bf_tr(s[10], s[11]);
            uint_t u6 = pack2bf_tr(s[12], s[13]), u7 = pack2bf_tr(s[14], s[15]);

            // sub-tile 0 (keys t*32 + 0..15):
            // low lanes need words {own u0, own u1, high u0, high u1}
            // high lanes need      {low u2, low u3, own u2, own u3}
            uint_t f0, f1, f2, f3;
            plswap(u2, u0, f2, f0);
            plswap(u3, u1, f3, f1);
            uint4v cv0; cv0[0] = f0; cv0[1] = f1; cv0[2] = f2; cv0[3] = f3;
            short8 pa0 = __builtin_bit_cast(short8, cv0);
            short8 vb0 = *(const short8*)&Vt[lane31 * 520 + t * 32 + lhalf * 8];
            oacc = __builtin_amdgcn_mfma_f32_32x32x16_bf16(pa0, vb0, oacc, 0, 0, 0);

            // sub-tile 1 (keys t*32 + 16..31)
            uint_t g0, g1, g2, g3;
            plswap(u6, u4, g2, g0);
            plswap(u7, u5, g3, g1);
            uint4v cv1; cv1[0] = g0; cv1[1] = g1; cv1[2] = g2; cv1[3] = g3;
            short8 pa1 = __builtin_bit_cast(short8, cv1);
            short8 vb1 = *(const short8*)&Vt[lane31 * 520 + t * 32 + 16 + lhalf * 8];
            oacc = __builtin_amdgcn_mfma_f32_32x32x16_bf16(pa1, vb1, oacc, 0, 0, 0);
        }

        // epilogue: C[row=q][col]: cols 0..15 = O[q][dk], col 16 = row-sum l[q]
#pragma unroll
        for (int r = 0; r < 16; r++) {
            const int qrow = (r & 3) + 8 * (r >> 2) + 4 * lhalf;
            const float lsum = __shfl(oacc[r], (L & 32) | 16);
            if (lane31 < 16)
                Aout[(size_t)(b * 512 + q0g + qrow) * 128 + h * 16 + lane31] = f2bf(oacc[r] / lsum);
        }
    }
}

// ---------------- fused layer tail v4: ping-pong double-buffered staging ----------------
// (exact R0/R3 config — measured-best)
__global__ __launch_bounds__(256, 2) void tail_kernel(
        const ushort_t* __restrict__ A,     // a16 [16384][128]
        const ushort_t* __restrict__ WoT,   // [128 n][128 k]
        const ushort_t* __restrict__ W1T,   // [512 n][128 k]
        const ushort_t* __restrict__ W2T,   // [128 n][512 k]
        const float* __restrict__ b1,
        const float* __restrict__ b2,
        float* __restrict__ hf, ushort_t* __restrict__ hb,
        float* __restrict__ pbsum, int accum) {
    __shared__ __align__(16) ushort_t sm[39424];   // 78.85 KB -> 2 blocks/CU
    ushort_t* AsA = sm;            // 1024  (32x32 chunk)
    ushort_t* AsB = sm + 1024;     // 1024
    ushort_t* BsA = sm + 2048;     // 8192  (up to 256x32 chunk)
    ushort_t* BsB = sm + 10240;    // 8192
    ushort_t* C1b = sm + 18432;    // 4352  (32x136)
    ushort_t* T   = sm + 22784;    // 16640 (32x520)

    const int tid = threadIdx.x;
    const int w = tid >> 6, l = tid & 63;
    const int lr = l & 15, lq = l >> 4;
    const int srow = (l >> 2);
    const int scol = (l & 3) * 8;
    const int m0 = blockIdx.x * 32;

    // ================ phase A: C1 = a16 @ WoT^T + h ================
    f32x4 c1a[2][2];
#pragma unroll
    for (int i = 0; i < 2; i++)
#pragma unroll
        for (int j = 0; j < 2; j++) c1a[i][j] = (f32x4){0.f, 0.f, 0.f, 0.f};
    // prologue: stage k0=0
    if (w < 2)
        gload16(A + (size_t)(m0 + w * 16 + srow) * 128 + scol, &AsA[(w * 16 + srow) * 32 + scol]);
#pragma unroll
    for (int it = 0; it < 2; it++)
        gload16(WoT + (size_t)(it * 64 + w * 16 + srow) * 128 + scol, &BsA[(it * 64 + w * 16 + srow) * 32 + scol]);
#pragma unroll
    for (int k0 = 0; k0 < 128; k0 += 32) {
        ushort_t* Ac = (k0 & 32) ? AsB : AsA;
        ushort_t* Bc = (k0 & 32) ? BsB : BsA;
        ushort_t* An = (k0 & 32) ? AsA : AsB;
        ushort_t* Bn = (k0 & 32) ? BsA : BsB;
        __syncthreads();   // chunk k0 staged; prior reads of An/Bn done
        if (k0 + 32 < 128) {
            if (w < 2)
                gload16(A + (size_t)(m0 + w * 16 + srow) * 128 + k0 + 32 + scol,
                        &An[(w * 16 + srow) * 32 + scol]);
#pragma unroll
            for (int it = 0; it < 2; it++)
                gload16(WoT + (size_t)(it * 64 + w * 16 + srow) * 128 + k0 + 32 + scol,
                        &Bn[(it * 64 + w * 16 + srow) * 32 + scol]);
        }
        short8 af[2], bfr[2];
#pragma unroll
        for (int i = 0; i < 2; i++) af[i] = *(const short8*)&Ac[(i * 16 + lr) * 32 + lq * 8];
#pragma unroll
        for (int j = 0; j < 2; j++) bfr[j] = *(const short8*)&Bc[(w * 32 + j * 16 + lr) * 32 + lq * 8];
#pragma unroll
        for (int i = 0; i < 2; i++)
#pragma unroll
            for (int j = 0; j < 2; j++)
                c1a[i][j] = __builtin_amdgcn_mfma_f32_16x16x32_bf16(af[i], bfr[j], c1a[i][j], 0, 0, 0);
    }
    // epilogue A: + residual h (fp32 regs + bf16 LDS)
    float c1[2][2][4];
#pragma unroll
    for (int i = 0; i < 2; i++)
#pragma unroll
        for (int r = 0; r < 4; r++) {
            const int row = i * 16 + lq * 4 + r;
#pragma unroll
            for (int j = 0; j < 2; j++) {
                const int n = w * 32 + j * 16 + lr;
                const float v = c1a[i][j][r] + hf[(size_t)(m0 + row) * 128 + n];
                c1[i][j][r] = v;
                C1b[row * 136 + n] = f2bf(v);
            }
        }

    // ================ phase B: T = relu(C1 @ W1T^T + b1), 2 n-halves x 4 k-chunks ================
#pragma unroll
    for (int it = 0; it < 4; it++)
        gload16(W1T + (size_t)(it * 64 + w * 16 + srow) * 128 + scol, &BsA[(it * 64 + w * 16 + srow) * 32 + scol]);
#pragma unroll
    for (int nc = 0; nc < 2; nc++) {
        f32x4 ta[2][4];
#pragma unroll
        for (int i = 0; i < 2; i++)
#pragma unroll
            for (int j = 0; j < 4; j++) ta[i][j] = (f32x4){0.f, 0.f, 0.f, 0.f};
#pragma unroll
        for (int k0i = 0; k0i < 4; k0i++) {
            const int c = nc * 4 + k0i;
            ushort_t* Bc = (c & 1) ? BsB : BsA;
            ushort_t* Bn = (c & 1) ? BsA : BsB;
            __syncthreads();   // chunk c staged; also orders C1b writes (first iter)
            if (c + 1 < 8) {
                const int nc2 = (c + 1) >> 2, k02 = ((c + 1) & 3) * 32;
#pragma unroll
                for (int it = 0; it < 4; it++)
                    gload16(W1T + (size_t)(nc2 * 256 + it * 64 + w * 16 + srow) * 128 + k02 + scol,
                            &Bn[(it * 64 + w * 16 + srow) * 32 + scol]);
            }
            short8 af[2], bfr[4];
#pragma unroll
            for (int i = 0; i < 2; i++)
                af[i] = *(const short8*)&C1b[(i * 16 + lr) * 136 + k0i * 32 + lq * 8];
#pragma unroll
            for (int j = 0; j < 4; j++)
                bfr[j] = *(const short8*)&Bc[(w * 64 + j * 16 + lr) * 32 + lq * 8];
#pragma unroll
            for (int i = 0; i < 2; i++)
#pragma unroll
                for (int j = 0; j < 4; j++)
                    ta[i][j] = __builtin_amdgcn_mfma_f32_16x16x32_bf16(af[i], bfr[j], ta[i][j], 0, 0, 0);
        }
        // epilogue nc: +b1, relu -> T (distinct region; staging for next chunk flies concurrently)
#pragma unroll
        for (int j = 0; j < 4; j++) {
            const int n = nc * 256 + w * 64 + j * 16 + lr;
            const float bv = b1[n];
#pragma unroll
            for (int i = 0; i < 2; i++)
#pragma unroll
                for (int r = 0; r < 4; r++) {
                    const int row = i * 16 + lq * 4 + r;
                    T[row * 520 + n] = f2bf(fmaxf(ta[i][j][r] + bv, 0.f));
                }
        }
    }

    // ================ phase C: h' = C1 + T @ W2T^T + b2, 16 k-chunks ================
#pragma unroll
    for (int it = 0; it < 2; it++)
        gload16(W2T + (size_t)(it * 64 + w * 16 + srow) * 512 + scol, &BsA[(it * 64 + w * 16 + srow) * 32 + scol]);
    f32x4 oa[2][2];
#pragma unroll
    for (int i = 0; i < 2; i++)
#pragma unroll
        for (int j = 0; j < 2; j++) oa[i][j] = (f32x4){0.f, 0.f, 0.f, 0.f};
#pragma unroll
    for (int k0 = 0; k0 < 512; k0 += 32) {
        ushort_t* Bc = ((k0 >> 5) & 1) ? BsB : BsA;
        ushort_t* Bn = ((k0 >> 5) & 1) ? BsA : BsB;
        __syncthreads();   // chunk staged; T writes ordered (first iter)
        if (k0 + 32 < 512) {
#pragma unroll
            for (int it = 0; it < 2; it++)
                gload16(W2T + (size_t)(it * 64 + w * 16 + srow) * 512 + k0 + 32 + scol,
                        &Bn[(it * 64 + w * 16 + srow) * 32 + scol]);
        }
        short8 af[2], bfr[2];
#pragma unroll
        for (int i = 0; i < 2; i++)
            af[i] = *(const short8*)&T[(i * 16 + lr) * 520 + k0 + lq * 8];
#pragma unroll
        for (int j = 0; j < 2; j++)
            bfr[j] = *(const short8*)&Bc[(w * 32 + j * 16 + lr) * 32 + lq * 8];
#pragma unroll
        for (int i = 0; i < 2; i++)
#pragma unroll
            for (int j = 0; j < 2; j++)
                oa[i][j] = __builtin_amdgcn_mfma_f32_16x16x32_bf16(af[i], bfr[j], oa[i][j], 0, 0, 0);
    }
    // epilogue C: + b2 + C1 -> global fp32 + bf16 (+ pooled-sum atomics on last layer)
#pragma unroll
    for (int j = 0; j < 2; j++) {
        const int n = w * 32 + j * 16 + lr;
        const float bv = b2[n];
        float psum = 0.f;
#pragma unroll
        for (int i = 0; i < 2; i++)
#pragma unroll
            for (int r = 0; r < 4; r++) {
                const int row = i * 16 + lq * 4 + r;
                const float v = oa[i][j][r] + bv + c1[i][j][r];
                psum += v;
                hf[(size_t)(m0 + row) * 128 + n] = v;
                hb[(size_t)(m0 + row) * 128 + n] = f2bf(v);
            }
        if (accum) {
            psum += __shfl_xor(psum, 16);
            psum += __shfl_xor(psum, 32);
            if (lq == 0) atomicAdd(&pbsum[(m0 >> 9) * 128 + n], psum);
        }
    }
}

// ------------- readout: 512 blocks, 32 rows each (unchanged) -------------
__global__ __launch_bounds__(256) void readout_kernel(const float* __restrict__ h,
                                                      const float* __restrict__ pbsum,
                                                      const float* __restrict__ Wp,
                                                      const float* __restrict__ Wr,
                                                      const float* __restrict__ br,
                                                      float* __restrict__ out) {
    const int u = blockIdx.x;
    const int b = u >> 4;
    const int m0 = u * 32;
    const int t = threadIdx.x;
    __shared__ float pooled[128];
    __shared__ float rp[128];
    __shared__ float pb3[3];
    if (t < 128) pooled[t] = pbsum[b * 128 + t] * (1.0f / 512.0f);
    __syncthreads();
    if (t < 128) {
        float a = 0.f;
        for (int dd = 0; dd < 128; dd++) a += pooled[dd] * Wp[dd * 128 + t];
        rp[t] = fmaxf(a, 0.f);
    }
    __syncthreads();
    if (t < OUT_DIM) {
        float a = br[t];
        for (int j = 0; j < 128; j++) a += rp[j] * Wr[j * 3 + t];
        pb3[t] = a;
    }
    __syncthreads();
    const int j = t & 7;
    const int row = m0 + (t >> 3);
    const float* hr = h + (size_t)row * 128 + j * 16;
    float a0 = 0.f, a1 = 0.f, a2o = 0.f;
#pragma unroll
    for (int dd = 0; dd < 16; dd++) {
        const float v = fmaxf(hr[dd], 0.f);
        const float* wr = Wr + (size_t)(128 + j * 16 + dd) * 3;
        a0 += v * wr[0]; a1 += v * wr[1]; a2o += v * wr[2];
    }
#pragma unroll
    for (int off = 4; off; off >>= 1) {
        a0 += __shfl_down(a0, off, 8);
        a1 += __shfl_down(a1, off, 8);
        a2o += __shfl_down(a2o, off, 8);
    }
    if (j == 0) {
        out[(size_t)row * 3 + 0] = a0 + pb3[0];
        out[(size_t)row * 3 + 1] = a1 + pb3[1];
        out[(size_t)row * 3 + 2] = a2o + pb3[2];
    }
}

extern "C" void kernel_launch(void* const* d_in, const int* in_sizes, int n_in,
                              void* d_out, int out_size, void* d_ws, size_t ws_size,
                              hipStream_t stream) {
    const float* x    = (const float*)d_in[0];
    const int*   mask = (const int*)d_in[1];
    const float* We   = (const float*)d_in[2];
    const float* Wq   = (const float*)d_in[3];
    const float* Wk   = (const float*)d_in[4];
    const float* Wv   = (const float*)d_in[5];
    const float* Wout = (const float*)d_in[6];
    const float* Wff1 = (const float*)d_in[7];
    const float* bff1 = (const float*)d_in[8];
    const float* Wff2 = (const float*)d_in[9];
    const float* bff2 = (const float*)d_in[10];
    const float* Wp   = (const float*)d_in[11];
    const float* Wr   = (const float*)d_in[12];
    const float* br   = (const float*)d_in[13];
    float* out = (float*)d_out;

    char* ws = (char*)d_ws;
    unsigned long long* pm64 = (unsigned long long*)(ws + 0);        // 1 MiB
    const uint_t* pm32       = (const uint_t*)(ws + 0);
    ushort_t* wqkvT = (ushort_t*)(ws + 1048576);
    ushort_t* woutT = (ushort_t*)(ws + 1343488);
    ushort_t* wff1T = (ushort_t*)(ws + 1441792);
    ushort_t* wff2T = (ushort_t*)(ws + 1835008);
    float*    pbsum = (float*)(ws + 2228224);                        // 16 KiB pooled sums
    float*    hbuf  = (float*)(ws + 4194304);                        // 8 MiB fp32 residual
    ushort_t* hb16  = (ushort_t*)(ws + 12582912);                    // 4 MiB bf16 mirror
    ushort_t* a16   = (ushort_t*)(ws + 41943040);                    // 4 MiB attn out

    preproc_kernel<<<PM_BLK + RQ_BLK + TW_BLK + T1_BLK + T2_BLK + PB_BLK + EM_BLK, 256, 0, stream>>>(
        mask, pm64, Wq, Wk, Wv, wqkvT, Wout, woutT, Wff1, wff1T, Wff2, wff2T,
        pbsum, x, We, hbuf, hb16);

    for (int l = 0; l < L_LAYERS; l++) {
        qkv_attn_kernel<<<256, 512, 0, stream>>>(
            hb16, wqkvT + (size_t)l * 384 * 128, pm32, a16);
        tail_kernel<<<M_ROWS / 32, 256, 0, stream>>>(
            a16, woutT + (size_t)l * 128 * 128, wff1T + (size_t)l * 512 * 128,
            wff2T + (size_t)l * 128 * 512, bff1 + l * 512, bff2 + l * 128,
            hbuf, hb16, pbsum, (l == L_LAYERS - 1) ? 1 : 0);
    }

    readout_kernel<<<512, 256, 0, stream>>>(hbuf, pbsum, Wp, Wr, br, out);
}

// Round 17
// 258.390 us; speedup vs baseline: 1.4032x; 1.0853x over previous
//
#include <hip/hip_runtime.h>
#include <cstdint>
#include <cstddef>

#define L_LAYERS 3
#define H_HEADS 8
#define D_EMB 128
#define DKV 16
#define FF_DIM 512
#define B_BATCH 32
#define N_SEQ 512
#define F_INP 16
#define OUT_DIM 3
#define M_ROWS (B_BATCH * N_SEQ)   // 16384
#define QSCALE 0.3606737602222409f // 0.25 * log2(e): scores in log2 domain

typedef unsigned short ushort_t;
typedef unsigned int uint_t;
typedef __attribute__((ext_vector_type(8))) short short8;
typedef __attribute__((ext_vector_type(4))) float f32x4;
typedef __attribute__((ext_vector_type(16))) float f32x16;

__device__ inline ushort_t f2bf(float x) {   // RNE float->bf16
    union { float f; uint_t u; } v; v.f = x;
    uint_t r = v.u + 0x7fffu + ((v.u >> 16) & 1u);
    return (ushort_t)(r >> 16);
}

__device__ inline uint_t pack2bf_tr(float a, float b) {  // truncating pack: lo=a, hi=b
    union { float f; uint_t u; } ua, ub;
    ua.f = a; ub.f = b;
#if __has_builtin(__builtin_amdgcn_perm)
    return __builtin_amdgcn_perm(ub.u, ua.u, 0x07060302u);  // 1 VALU op, bit-identical
#else
    return (ua.u >> 16) | (ub.u & 0xffff0000u);
#endif
}

__device__ inline float exp2fast(float x) {   // raw v_exp_f32 (2^x)
#if __has_builtin(__builtin_amdgcn_exp2f)
    return __builtin_amdgcn_exp2f(x);
#else
    float r; __asm__("v_exp_f32 %0, %1" : "=v"(r) : "v"(x)); return r;
#endif
}

__device__ inline void gload16(const void* g, void* l) {
    __builtin_amdgcn_global_load_lds(
        (const __attribute__((address_space(1))) unsigned int*)g,
        (__attribute__((address_space(3))) unsigned int*)l, 16, 0, 0);
}

// ---------------- fused preprocessing v2 (R7 config) ----------------
#define PM_BLK 2048    // x16 chunks each
#define RQ_BLK 576
#define TW_BLK 192
#define T1_BLK 768
#define T2_BLK 768
#define PB_BLK 16
#define EM_BLK 1024    // x8 row-pairs each
__global__ __launch_bounds__(256) void preproc_kernel(
        const int* __restrict__ mask, unsigned long long* __restrict__ pm,
        const float* __restrict__ Wq, const float* __restrict__ Wk,
        const float* __restrict__ Wv, ushort_t* __restrict__ wqkvT,
        const float* __restrict__ Wout, ushort_t* __restrict__ woutT,
        const float* __restrict__ Wff1, ushort_t* __restrict__ wff1T,
        const float* __restrict__ Wff2, ushort_t* __restrict__ wff2T,
        float* __restrict__ pbsum,
        const float* __restrict__ x, const float* __restrict__ We,
        float* __restrict__ hf, ushort_t* __restrict__ hb) {
    int bx = blockIdx.x;
    const int tid = threadIdx.x;
    if (bx < PM_BLK) {
#pragma unroll 4
        for (int it = 0; it < 16; ++it) {
            const int gid = (bx * 16 + it) * 256 + tid;
            const int v = mask[gid];
            const unsigned long long bal = __ballot(v != 0);
            if ((tid & 63) == 0) pm[gid >> 6] = bal;
        }
        return;
    }
    bx -= PM_BLK;
    if (bx < RQ_BLK) {
        int idx = bx * 256 + tid;
        int d = idx & 127;
        int n = (idx >> 7) % 384;
        int l = idx / (384 * 128);
        int proj = n >> 7, hh = (n & 127) >> 4, kk = n & 15;
        const float* src = proj == 0 ? Wq : proj == 1 ? Wk : Wv;
        wqkvT[idx] = f2bf(src[((size_t)(l * 8 + hh) * 128 + d) * 16 + kk]);
        return;
    }
    bx -= RQ_BLK;
    if (bx < TW_BLK + T1_BLK + T2_BLK) {
        const float* src; ushort_t* dst; int R, C;
        if (bx < TW_BLK) { src = Wout; dst = woutT; R = 128; C = 128; }
        else if (bx < TW_BLK + T1_BLK) { src = Wff1; dst = wff1T; R = 128; C = 512; bx -= TW_BLK; }
        else { src = Wff2; dst = wff2T; R = 512; C = 128; bx -= TW_BLK + T1_BLK; }
        int idx = bx * 256 + tid;
        int b = idx / (R * C);
        int rem = idx - b * (R * C);
        int c = rem / R, r = rem - c * R;
        dst[idx] = f2bf(src[((size_t)b * R + r) * C + c]);
        return;
    }
    bx -= TW_BLK + T1_BLK + T2_BLK;
    if (bx < PB_BLK) {
        pbsum[bx * 256 + tid] = 0.f;
        return;
    }
    bx -= PB_BLK;
    {
        const int d = tid & 127;
#pragma unroll 2
        for (int it = 0; it < 8; ++it) {
            const int m = (bx * 8 + it) * 2 + (tid >> 7);
            const float* xr = x + (size_t)m * 16;
            float acc = 0.f;
#pragma unroll
            for (int k = 0; k < 16; k++) acc += xr[k] * We[k * 128 + d];
            acc = fmaxf(acc, 0.f);
            hf[(size_t)m * 128 + d] = acc;
            hb[(size_t)m * 128 + d] = f2bf(acc);
        }
    }
}

// ---------------- fused QKV-GEMM + flash attention v12b ----------------
// v12b = R11's measured-best v12 (262.6 us: merged halves, Qs->qf registers,
// Ps double-buffer aliasing Qs/Ws, 69.9 KB LDS -> 2 blocks/CU) + ONE tweak:
// XCD-major block relabel u = ((bx&7)<<5)|(bx>>3) (bijective on 256). Default
// order put the 8 heads of one batch (sharing the same 128 KB Ab panel) on 8
// DIFFERENT XCD L2s -> 8x panel over-fetch (R10: FETCH 28.6MB vs 4.2MB input).
// Relabel gives each XCD 4 complete batches -> panel fetched once per XCD.
__global__ __launch_bounds__(512, 4) void qkv_attn_kernel(
        const ushort_t* __restrict__ hb,    // [16384][128] bf16
        const ushort_t* __restrict__ WqkvT, // layer slice [384][128] bf16 B^T
        const uint_t* __restrict__ pm,      // packed mask
        ushort_t* __restrict__ Aout) {      // [16384][128] bf16
    __shared__ __align__(16) ushort_t sm[34944];   // 69.9 KB -> 2 blocks/CU
    ushort_t* KF  = sm;            // 8192u  (16 tiles * 512)
    ushort_t* Vt  = sm + 8192;     // 8320u  [16][520]
    ushort_t* Qs  = sm + 16512;    // 8192u  [512][16]  (phase 1 out; freed after qf load)
    ushort_t* Ws  = sm + 24704;    // 6144u  [48][128]  (phase 1 weights)
    ushort_t* PsA = sm + 16512;    // 9216u  (phase 2; aliases Qs + Ws head)
    ushort_t* PsB = sm + 25728;    // 9216u  (aliases Ws tail)

    const int tid = threadIdx.x;
    const int w = tid >> 6, L = tid & 63;
    const int lr = L & 15, lq = L >> 4;
    const int lane31 = L & 31, lhalf = L >> 5;
    const int bx = blockIdx.x;
    const int u = ((bx & 7) << 5) | (bx >> 3);   // XCD-major relabel (T1)
    const int b = u >> 3, h = u & 7;

    for (int i = tid; i < 768; i += 512) {
        const int row = i >> 4, cg = i & 15;
        const int proj = row >> 4, kk = row & 15;
        gload16(WqkvT + (size_t)(proj * 128 + h * 16 + kk) * 128 + cg * 8, &Ws[i * 8]);
    }
    __syncthreads();

    const ushort_t* Ab = hb + (size_t)b * 512 * 128;
    for (int mc = 0; mc < 4; mc++) {
        f32x4 acc[3];
#pragma unroll
        for (int j = 0; j < 3; j++) acc[j] = (f32x4){0.f, 0.f, 0.f, 0.f};
#pragma unroll
        for (int k0 = 0; k0 < 128; k0 += 32) {
            short8 af = *(const short8*)(Ab + (size_t)(mc * 128 + w * 16 + lr) * 128 + k0 + lq * 8);
#pragma unroll
            for (int j = 0; j < 3; j++) {
                short8 bf = *(const short8*)&Ws[(j * 16 + lr) * 128 + k0 + lq * 8];
                acc[j] = __builtin_amdgcn_mfma_f32_16x16x32_bf16(af, bf, acc[j], 0, 0, 0);
            }
        }
        const int rbase = mc * 128 + w * 16 + lq * 4;
#pragma unroll
        for (int r = 0; r < 4; r++) {
            const int key = rbase + r;
            KF[(key >> 5) * 512 + ((lr >> 3) * 32 + (key & 31)) * 8 + (lr & 7)] = f2bf(acc[1][r]);
            Vt[lr * 520 + key] = f2bf(acc[2][r]);
            Qs[(key) * 16 + lr] = f2bf(acc[0][r] * QSCALE);
        }
    }
    __syncthreads();   // KF/Vt/Qs complete

    // pull BOTH q-fragments into registers, then free Qs for Ps reuse
    const short8 qf0 = *(const short8*)&Qs[(w * 32 + lane31) * 16 + lhalf * 8];
    const short8 qf1 = *(const short8*)&Qs[(256 + w * 32 + lane31) * 16 + lhalf * 8];
    __syncthreads();   // qf reads done; Qs/Ws regions now writable as PsA/PsB

    const f32x16 zero16 = (f32x16)(0.f);
    short8 vone;
#pragma unroll
    for (int i = 0; i < 8; i++) vone[i] = (short)0x3F80;   // bf16 1.0

// score-compute for tile T into PS: QK-MFMA, exp/mask, pack, ds_write
#define CS_STEP(T_IDX, PS) do {                                                     \
    short8 kf = *(const short8*)&KF[(T_IDX) * 512 + L * 8];                         \
    f32x16 s = __builtin_amdgcn_mfma_f32_32x32x16_bf16(kf, qf, zero16, 0, 0, 0);    \
    const uint_t word = mw[(T_IDX)];                                                \
    _Pragma("unroll")                                                               \
    for (int r = 0; r < 16; r++) {                                                  \
        const int keyl = (r & 3) + 8 * (r >> 2) + 4 * lhalf;                        \
        const float e = exp2fast(s[r]);                                             \
        s[r] = (word & (1u << keyl)) ? e : 0.f;                                     \
    }                                                                               \
    _Pragma("unroll")                                                               \
    for (int g = 0; g < 4; g++) {                                                   \
        const uint_t lo = pack2bf_tr(s[g * 4 + 0], s[g * 4 + 1]);                   \
        const uint_t hi = pack2bf_tr(s[g * 4 + 2], s[g * 4 + 3]);                   \
        *(uint2*)&(PS)[w * 1152 + lane31 * 36 + g * 8 + 4 * lhalf] = make_uint2(lo, hi); \
    }                                                                               \
} while (0)

// PV accumulate for tile T from PS (reads + 4 MFMAs)
#define PV_STEP(T_IDX, PS) do {                                                     \
    short8 vb = *(const short8*)&Vt[lr * 520 + (T_IDX) * 32 + lq * 8];              \
    short8 pa0 = *(const short8*)&(PS)[w * 1152 + lr * 36 + lq * 8];                \
    short8 pa1 = *(const short8*)&(PS)[w * 1152 + (16 + lr) * 36 + lq * 8];         \
    oacc0 = __builtin_amdgcn_mfma_f32_16x16x32_bf16(pa0, vb, oacc0, 0, 0, 0);       \
    oacc1 = __builtin_amdgcn_mfma_f32_16x16x32_bf16(pa1, vb, oacc1, 0, 0, 0);       \
    lacc0 = __builtin_amdgcn_mfma_f32_16x16x32_bf16(pa0, vone, lacc0, 0, 0, 0);     \
    lacc1 = __builtin_amdgcn_mfma_f32_16x16x32_bf16(pa1, vone, lacc1, 0, 0, 0);     \
} while (0)

// pipelined body: PV(T-1) ds_reads issued BEFORE CS(T)'s ds_writes
#define PIPE_STEP(T_IDX, PSCUR, PSPREV) do {                                        \
    short8 kf = *(const short8*)&KF[(T_IDX) * 512 + L * 8];                         \
    f32x16 s = __builtin_amdgcn_mfma_f32_32x32x16_bf16(kf, qf, zero16, 0, 0, 0);    \
    PV_STEP((T_IDX) - 1, PSPREV);                                                   \
    const uint_t word = mw[(T_IDX)];                                                \
    _Pragma("unroll")                                                               \
    for (int r = 0; r < 16; r++) {                                                  \
        const int keyl = (r & 3) + 8 * (r >> 2) + 4 * lhalf;                        \
        const float e = exp2fast(s[r]);                                             \
        s[r] = (word & (1u << keyl)) ? e : 0.f;                                     \
    }                                                                               \
    _Pragma("unroll")                                                               \
    for (int g = 0; g < 4; g++) {                                                   \
        const uint_t lo = pack2bf_tr(s[g * 4 + 0], s[g * 4 + 1]);                   \
        const uint_t hi = pack2bf_tr(s[g * 4 + 2], s[g * 4 + 3]);                   \
        *(uint2*)&(PSCUR)[w * 1152 + lane31 * 36 + g * 8 + 4 * lhalf] = make_uint2(lo, hi); \
    }                                                                               \
} while (0)

    for (int qloop = 0; qloop < 2; ++qloop) {
        const int q0g = qloop * 256 + w * 32;
        const short8 qf = qloop ? qf1 : qf0;
        const uint_t* pmr = pm + (size_t)(b * 512 + q0g + lane31) * 16;
        const uint4 mwa = *(const uint4*)(pmr);
        const uint4 mwb = *(const uint4*)(pmr + 4);
        const uint4 mwc = *(const uint4*)(pmr + 8);
        const uint4 mwd = *(const uint4*)(pmr + 12);
        const uint_t mw[16] = {mwa.x, mwa.y, mwa.z, mwa.w, mwb.x, mwb.y, mwb.z, mwb.w,
                               mwc.x, mwc.y, mwc.z, mwc.w, mwd.x, mwd.y, mwd.z, mwd.w};

        f32x4 oacc0 = (f32x4){0.f, 0.f, 0.f, 0.f};
        f32x4 oacc1 = (f32x4){0.f, 0.f, 0.f, 0.f};
        f32x4 lacc0 = (f32x4){0.f, 0.f, 0.f, 0.f};
        f32x4 lacc1 = (f32x4){0.f, 0.f, 0.f, 0.f};

        CS_STEP(0, PsA);
#pragma unroll
        for (int tp = 0; tp < 7; tp++) {
            PIPE_STEP(2 * tp + 1, PsB, PsA);
            PIPE_STEP(2 * tp + 2, PsA, PsB);
        }
        PIPE_STEP(15, PsB, PsA);
        PV_STEP(15, PsB);

#pragma unroll
        for (int qa = 0; qa < 2; qa++) {
            const f32x4 oa = qa ? oacc1 : oacc0;
            const f32x4 la = qa ? lacc1 : lacc0;
#pragma unroll
            for (int rr = 0; rr < 4; rr++) {
                const int qloc = qa * 16 + lq * 4 + rr;
                Aout[(size_t)(b * 512 + q0g + qloc) * 128 + h * 16 + lr] = f2bf(oa[rr] / la[rr]);
            }
        }
    }
#undef CS_STEP
#undef PV_STEP
#undef PIPE_STEP
}

// ---------------- fused layer tail v4: ping-pong double-buffered staging ----------------
// (exact R0/R3 config — measured-best)
__global__ __launch_bounds__(256, 2) void tail_kernel(
        const ushort_t* __restrict__ A,     // a16 [16384][128]
        const ushort_t* __restrict__ WoT,   // [128 n][128 k]
        const ushort_t* __restrict__ W1T,   // [512 n][128 k]
        const ushort_t* __restrict__ W2T,   // [128 n][512 k]
        const float* __restrict__ b1,
        const float* __restrict__ b2,
        float* __restrict__ hf, ushort_t* __restrict__ hb,
        float* __restrict__ pbsum, int accum) {
    __shared__ __align__(16) ushort_t sm[39424];   // 78.85 KB -> 2 blocks/CU
    ushort_t* AsA = sm;            // 1024  (32x32 chunk)
    ushort_t* AsB = sm + 1024;     // 1024
    ushort_t* BsA = sm + 2048;     // 8192  (up to 256x32 chunk)
    ushort_t* BsB = sm + 10240;    // 8192
    ushort_t* C1b = sm + 18432;    // 4352  (32x136)
    ushort_t* T   = sm + 22784;    // 16640 (32x520)

    const int tid = threadIdx.x;
    const int w = tid >> 6, l = tid & 63;
    const int lr = l & 15, lq = l >> 4;
    const int srow = (l >> 2);
    const int scol = (l & 3) * 8;
    const int m0 = blockIdx.x * 32;

    // ================ phase A: C1 = a16 @ WoT^T + h ================
    f32x4 c1a[2][2];
#pragma unroll
    for (int i = 0; i < 2; i++)
#pragma unroll
        for (int j = 0; j < 2; j++) c1a[i][j] = (f32x4){0.f, 0.f, 0.f, 0.f};
    // prologue: stage k0=0
    if (w < 2)
        gload16(A + (size_t)(m0 + w * 16 + srow) * 128 + scol, &AsA[(w * 16 + srow) * 32 + scol]);
#pragma unroll
    for (int it = 0; it < 2; it++)
        gload16(WoT + (size_t)(it * 64 + w * 16 + srow) * 128 + scol, &BsA[(it * 64 + w * 16 + srow) * 32 + scol]);
#pragma unroll
    for (int k0 = 0; k0 < 128; k0 += 32) {
        ushort_t* Ac = (k0 & 32) ? AsB : AsA;
        ushort_t* Bc = (k0 & 32) ? BsB : BsA;
        ushort_t* An = (k0 & 32) ? AsA : AsB;
        ushort_t* Bn = (k0 & 32) ? BsA : BsB;
        __syncthreads();   // chunk k0 staged; prior reads of An/Bn done
        if (k0 + 32 < 128) {
            if (w < 2)
                gload16(A + (size_t)(m0 + w * 16 + srow) * 128 + k0 + 32 + scol,
                        &An[(w * 16 + srow) * 32 + scol]);
#pragma unroll
            for (int it = 0; it < 2; it++)
                gload16(WoT + (size_t)(it * 64 + w * 16 + srow) * 128 + k0 + 32 + scol,
                        &Bn[(it * 64 + w * 16 + srow) * 32 + scol]);
        }
        short8 af[2], bfr[2];
#pragma unroll
        for (int i = 0; i < 2; i++) af[i] = *(const short8*)&Ac[(i * 16 + lr) * 32 + lq * 8];
#pragma unroll
        for (int j = 0; j < 2; j++) bfr[j] = *(const short8*)&Bc[(w * 32 + j * 16 + lr) * 32 + lq * 8];
#pragma unroll
        for (int i = 0; i < 2; i++)
#pragma unroll
            for (int j = 0; j < 2; j++)
                c1a[i][j] = __builtin_amdgcn_mfma_f32_16x16x32_bf16(af[i], bfr[j], c1a[i][j], 0, 0, 0);
    }
    // epilogue A: + residual h (fp32 regs + bf16 LDS)
    float c1[2][2][4];
#pragma unroll
    for (int i = 0; i < 2; i++)
#pragma unroll
        for (int r = 0; r < 4; r++) {
            const int row = i * 16 + lq * 4 + r;
#pragma unroll
            for (int j = 0; j < 2; j++) {
                const int n = w * 32 + j * 16 + lr;
                const float v = c1a[i][j][r] + hf[(size_t)(m0 + row) * 128 + n];
                c1[i][j][r] = v;
                C1b[row * 136 + n] = f2bf(v);
            }
        }

    // ================ phase B: T = relu(C1 @ W1T^T + b1), 2 n-halves x 4 k-chunks ================
#pragma unroll
    for (int it = 0; it < 4; it++)
        gload16(W1T + (size_t)(it * 64 + w * 16 + srow) * 128 + scol, &BsA[(it * 64 + w * 16 + srow) * 32 + scol]);
#pragma unroll
    for (int nc = 0; nc < 2; nc++) {
        f32x4 ta[2][4];
#pragma unroll
        for (int i = 0; i < 2; i++)
#pragma unroll
            for (int j = 0; j < 4; j++) ta[i][j] = (f32x4){0.f, 0.f, 0.f, 0.f};
#pragma unroll
        for (int k0i = 0; k0i < 4; k0i++) {
            const int c = nc * 4 + k0i;
            ushort_t* Bc = (c & 1) ? BsB : BsA;
            ushort_t* Bn = (c & 1) ? BsA : BsB;
            __syncthreads();   // chunk c staged; also orders C1b writes (first iter)
            if (c + 1 < 8) {
                const int nc2 = (c + 1) >> 2, k02 = ((c + 1) & 3) * 32;
#pragma unroll
                for (int it = 0; it < 4; it++)
                    gload16(W1T + (size_t)(nc2 * 256 + it * 64 + w * 16 + srow) * 128 + k02 + scol,
                            &Bn[(it * 64 + w * 16 + srow) * 32 + scol]);
            }
            short8 af[2], bfr[4];
#pragma unroll
            for (int i = 0; i < 2; i++)
                af[i] = *(const short8*)&C1b[(i * 16 + lr) * 136 + k0i * 32 + lq * 8];
#pragma unroll
            for (int j = 0; j < 4; j++)
                bfr[j] = *(const short8*)&Bc[(w * 64 + j * 16 + lr) * 32 + lq * 8];
#pragma unroll
            for (int i = 0; i < 2; i++)
#pragma unroll
                for (int j = 0; j < 4; j++)
                    ta[i][j] = __builtin_amdgcn_mfma_f32_16x16x32_bf16(af[i], bfr[j], ta[i][j], 0, 0, 0);
        }
        // epilogue nc: +b1, relu -> T (distinct region; staging for next chunk flies concurrently)
#pragma unroll
        for (int j = 0; j < 4; j++) {
            const int n = nc * 256 + w * 64 + j * 16 + lr;
            const float bv = b1[n];
#pragma unroll
            for (int i = 0; i < 2; i++)
#pragma unroll
                for (int r = 0; r < 4; r++) {
                    const int row = i * 16 + lq * 4 + r;
                    T[row * 520 + n] = f2bf(fmaxf(ta[i][j][r] + bv, 0.f));
                }
        }
    }

    // ================ phase C: h' = C1 + T @ W2T^T + b2, 16 k-chunks ================
#pragma unroll
    for (int it = 0; it < 2; it++)
        gload16(W2T + (size_t)(it * 64 + w * 16 + srow) * 512 + scol, &BsA[(it * 64 + w * 16 + srow) * 32 + scol]);
    f32x4 oa[2][2];
#pragma unroll
    for (int i = 0; i < 2; i++)
#pragma unroll
        for (int j = 0; j < 2; j++) oa[i][j] = (f32x4){0.f, 0.f, 0.f, 0.f};
#pragma unroll
    for (int k0 = 0; k0 < 512; k0 += 32) {
        ushort_t* Bc = ((k0 >> 5) & 1) ? BsB : BsA;
        ushort_t* Bn = ((k0 >> 5) & 1) ? BsA : BsB;
        __syncthreads();   // chunk staged; T writes ordered (first iter)
        if (k0 + 32 < 512) {
#pragma unroll
            for (int it = 0; it < 2; it++)
                gload16(W2T + (size_t)(it * 64 + w * 16 + srow) * 512 + k0 + 32 + scol,
                        &Bn[(it * 64 + w * 16 + srow) * 32 + scol]);
        }
        short8 af[2], bfr[2];
#pragma unroll
        for (int i = 0; i < 2; i++)
            af[i] = *(const short8*)&T[(i * 16 + lr) * 520 + k0 + lq * 8];
#pragma unroll
        for (int j = 0; j < 2; j++)
            bfr[j] = *(const short8*)&Bc[(w * 32 + j * 16 + lr) * 32 + lq * 8];
#pragma unroll
        for (int i = 0; i < 2; i++)
#pragma unroll
            for (int j = 0; j < 2; j++)
                oa[i][j] = __builtin_amdgcn_mfma_f32_16x16x32_bf16(af[i], bfr[j], oa[i][j], 0, 0, 0);
    }
    // epilogue C: + b2 + C1 -> global fp32 + bf16 (+ pooled-sum atomics on last layer)
#pragma unroll
    for (int j = 0; j < 2; j++) {
        const int n = w * 32 + j * 16 + lr;
        const float bv = b2[n];
        float psum = 0.f;
#pragma unroll
        for (int i = 0; i < 2; i++)
#pragma unroll
            for (int r = 0; r < 4; r++) {
                const int row = i * 16 + lq * 4 + r;
                const float v = oa[i][j][r] + bv + c1[i][j][r];
                psum += v;
                hf[(size_t)(m0 + row) * 128 + n] = v;
                hb[(size_t)(m0 + row) * 128 + n] = f2bf(v);
            }
        if (accum) {
            psum += __shfl_xor(psum, 16);
            psum += __shfl_xor(psum, 32);
            if (lq == 0) atomicAdd(&pbsum[(m0 >> 9) * 128 + n], psum);
        }
    }
}

// ------------- readout: 512 blocks, 32 rows each (unchanged) -------------
__global__ __launch_bounds__(256) void readout_kernel(const float* __restrict__ h,
                                                      const float* __restrict__ pbsum,
                                                      const float* __restrict__ Wp,
                                                      const float* __restrict__ Wr,
                                                      const float* __restrict__ br,
                                                      float* __restrict__ out) {
    const int u = blockIdx.x;
    const int b = u >> 4;
    const int m0 = u * 32;
    const int t = threadIdx.x;
    __shared__ float pooled[128];
    __shared__ float rp[128];
    __shared__ float pb3[3];
    if (t < 128) pooled[t] = pbsum[b * 128 + t] * (1.0f / 512.0f);
    __syncthreads();
    if (t < 128) {
        float a = 0.f;
        for (int dd = 0; dd < 128; dd++) a += pooled[dd] * Wp[dd * 128 + t];
        rp[t] = fmaxf(a, 0.f);
    }
    __syncthreads();
    if (t < OUT_DIM) {
        float a = br[t];
        for (int j = 0; j < 128; j++) a += rp[j] * Wr[j * 3 + t];
        pb3[t] = a;
    }
    __syncthreads();
    const int j = t & 7;
    const int row = m0 + (t >> 3);
    const float* hr = h + (size_t)row * 128 + j * 16;
    float a0 = 0.f, a1 = 0.f, a2o = 0.f;
#pragma unroll
    for (int dd = 0; dd < 16; dd++) {
        const float v = fmaxf(hr[dd], 0.f);
        const float* wr = Wr + (size_t)(128 + j * 16 + dd) * 3;
        a0 += v * wr[0]; a1 += v * wr[1]; a2o += v * wr[2];
    }
#pragma unroll
    for (int off = 4; off; off >>= 1) {
        a0 += __shfl_down(a0, off, 8);
        a1 += __shfl_down(a1, off, 8);
        a2o += __shfl_down(a2o, off, 8);
    }
    if (j == 0) {
        out[(size_t)row * 3 + 0] = a0 + pb3[0];
        out[(size_t)row * 3 + 1] = a1 + pb3[1];
        out[(size_t)row * 3 + 2] = a2o + pb3[2];
    }
}

extern "C" void kernel_launch(void* const* d_in, const int* in_sizes, int n_in,
                              void* d_out, int out_size, void* d_ws, size_t ws_size,
                              hipStream_t stream) {
    const float* x    = (const float*)d_in[0];
    const int*   mask = (const int*)d_in[1];
    const float* We   = (const float*)d_in[2];
    const float* Wq   = (const float*)d_in[3];
    const float* Wk   = (const float*)d_in[4];
    const float* Wv   = (const float*)d_in[5];
    const float* Wout = (const float*)d_in[6];
    const float* Wff1 = (const float*)d_in[7];
    const float* bff1 = (const float*)d_in[8];
    const float* Wff2 = (const float*)d_in[9];
    const float* bff2 = (const float*)d_in[10];
    const float* Wp   = (const float*)d_in[11];
    const float* Wr   = (const float*)d_in[12];
    const float* br   = (const float*)d_in[13];
    float* out = (float*)d_out;

    char* ws = (char*)d_ws;
    unsigned long long* pm64 = (unsigned long long*)(ws + 0);        // 1 MiB
    const uint_t* pm32       = (const uint_t*)(ws + 0);
    ushort_t* wqkvT = (ushort_t*)(ws + 1048576);
    ushort_t* woutT = (ushort_t*)(ws + 1343488);
    ushort_t* wff1T = (ushort_t*)(ws + 1441792);
    ushort_t* wff2T = (ushort_t*)(ws + 1835008);
    float*    pbsum = (float*)(ws + 2228224);                        // 16 KiB pooled sums
    float*    hbuf  = (float*)(ws + 4194304);                        // 8 MiB fp32 residual
    ushort_t* hb16  = (ushort_t*)(ws + 12582912);                    // 4 MiB bf16 mirror
    ushort_t* a16   = (ushort_t*)(ws + 41943040);                    // 4 MiB attn out

    preproc_kernel<<<PM_BLK + RQ_BLK + TW_BLK + T1_BLK + T2_BLK + PB_BLK + EM_BLK, 256, 0, stream>>>(
        mask, pm64, Wq, Wk, Wv, wqkvT, Wout, woutT, Wff1, wff1T, Wff2, wff2T,
        pbsum, x, We, hbuf, hb16);

    for (int l = 0; l < L_LAYERS; l++) {
        qkv_attn_kernel<<<256, 512, 0, stream>>>(
            hb16, wqkvT + (size_t)l * 384 * 128, pm32, a16);
        tail_kernel<<<M_ROWS / 32, 256, 0, stream>>>(
            a16, woutT + (size_t)l * 128 * 128, wff1T + (size_t)l * 512 * 128,
            wff2T + (size_t)l * 128 * 512, bff1 + l * 512, bff2 + l * 128,
            hbuf, hb16, pbsum, (l == L_LAYERS - 1) ? 1 : 0);
    }

    readout_kernel<<<512, 256, 0, stream>>>(hbuf, pbsum, Wp, Wr, br, out);
}

// Round 18
// 257.204 us; speedup vs baseline: 1.4097x; 1.0046x over previous
//
#include <hip/hip_runtime.h>
#include <cstdint>
#include <cstddef>

#define L_LAYERS 3
#define H_HEADS 8
#define D_EMB 128
#define DKV 16
#define FF_DIM 512
#define B_BATCH 32
#define N_SEQ 512
#define F_INP 16
#define OUT_DIM 3
#define M_ROWS (B_BATCH * N_SEQ)   // 16384
#define QSCALE 0.3606737602222409f // 0.25 * log2(e): scores in log2 domain

typedef unsigned short ushort_t;
typedef unsigned int uint_t;
typedef __attribute__((ext_vector_type(8))) short short8;
typedef __attribute__((ext_vector_type(4))) float f32x4;
typedef __attribute__((ext_vector_type(16))) float f32x16;

__device__ inline ushort_t f2bf(float x) {   // RNE float->bf16
    union { float f; uint_t u; } v; v.f = x;
    uint_t r = v.u + 0x7fffu + ((v.u >> 16) & 1u);
    return (ushort_t)(r >> 16);
}

__device__ inline uint_t pack2bf_tr(float a, float b) {  // truncating pack: lo=a, hi=b
    union { float f; uint_t u; } ua, ub;
    ua.f = a; ub.f = b;
#if __has_builtin(__builtin_amdgcn_perm)
    return __builtin_amdgcn_perm(ub.u, ua.u, 0x07060302u);  // 1 VALU op, bit-identical
#else
    return (ua.u >> 16) | (ub.u & 0xffff0000u);
#endif
}

__device__ inline float exp2fast(float x) {   // raw v_exp_f32 (2^x)
#if __has_builtin(__builtin_amdgcn_exp2f)
    return __builtin_amdgcn_exp2f(x);
#else
    float r; __asm__("v_exp_f32 %0, %1" : "=v"(r) : "v"(x)); return r;
#endif
}

__device__ inline void gload16(const void* g, void* l) {
    __builtin_amdgcn_global_load_lds(
        (const __attribute__((address_space(1))) unsigned int*)g,
        (__attribute__((address_space(3))) unsigned int*)l, 16, 0, 0);
}

// ---------------- fused preprocessing v2 (R7 config) ----------------
#define PM_BLK 2048    // x16 chunks each
#define RQ_BLK 576
#define TW_BLK 192
#define T1_BLK 768
#define T2_BLK 768
#define PB_BLK 16
#define EM_BLK 1024    // x8 row-pairs each
__global__ __launch_bounds__(256) void preproc_kernel(
        const int* __restrict__ mask, unsigned long long* __restrict__ pm,
        const float* __restrict__ Wq, const float* __restrict__ Wk,
        const float* __restrict__ Wv, ushort_t* __restrict__ wqkvT,
        const float* __restrict__ Wout, ushort_t* __restrict__ woutT,
        const float* __restrict__ Wff1, ushort_t* __restrict__ wff1T,
        const float* __restrict__ Wff2, ushort_t* __restrict__ wff2T,
        float* __restrict__ pbsum,
        const float* __restrict__ x, const float* __restrict__ We,
        float* __restrict__ hf, ushort_t* __restrict__ hb) {
    int bx = blockIdx.x;
    const int tid = threadIdx.x;
    if (bx < PM_BLK) {
#pragma unroll 4
        for (int it = 0; it < 16; ++it) {
            const int gid = (bx * 16 + it) * 256 + tid;
            const int v = mask[gid];
            const unsigned long long bal = __ballot(v != 0);
            if ((tid & 63) == 0) pm[gid >> 6] = bal;
        }
        return;
    }
    bx -= PM_BLK;
    if (bx < RQ_BLK) {
        int idx = bx * 256 + tid;
        int d = idx & 127;
        int n = (idx >> 7) % 384;
        int l = idx / (384 * 128);
        int proj = n >> 7, hh = (n & 127) >> 4, kk = n & 15;
        const float* src = proj == 0 ? Wq : proj == 1 ? Wk : Wv;
        wqkvT[idx] = f2bf(src[((size_t)(l * 8 + hh) * 128 + d) * 16 + kk]);
        return;
    }
    bx -= RQ_BLK;
    if (bx < TW_BLK + T1_BLK + T2_BLK) {
        const float* src; ushort_t* dst; int R, C;
        if (bx < TW_BLK) { src = Wout; dst = woutT; R = 128; C = 128; }
        else if (bx < TW_BLK + T1_BLK) { src = Wff1; dst = wff1T; R = 128; C = 512; bx -= TW_BLK; }
        else { src = Wff2; dst = wff2T; R = 512; C = 128; bx -= TW_BLK + T1_BLK; }
        int idx = bx * 256 + tid;
        int b = idx / (R * C);
        int rem = idx - b * (R * C);
        int c = rem / R, r = rem - c * R;
        dst[idx] = f2bf(src[((size_t)b * R + r) * C + c]);
        return;
    }
    bx -= TW_BLK + T1_BLK + T2_BLK;
    if (bx < PB_BLK) {
        pbsum[bx * 256 + tid] = 0.f;
        return;
    }
    bx -= PB_BLK;
    {
        const int d = tid & 127;
#pragma unroll 2
        for (int it = 0; it < 8; ++it) {
            const int m = (bx * 8 + it) * 2 + (tid >> 7);
            const float* xr = x + (size_t)m * 16;
            float acc = 0.f;
#pragma unroll
            for (int k = 0; k < 16; k++) acc += xr[k] * We[k * 128 + d];
            acc = fmaxf(acc, 0.f);
            hf[(size_t)m * 128 + d] = acc;
            hb[(size_t)m * 128 + d] = f2bf(acc);
        }
    }
}

// ---------------- fused QKV-GEMM + flash attention v12c ----------------
// v12c = R17's best v12b (258.4 us: merged halves, qf registers, Ps dbuf,
// 69.9 KB LDS -> 2 blocks/CU, XCD-major relabel) + ONE tweak: the resident
// mw[16] mask array (16 VGPRs) is replaced by per-step dword loads from the
// L2-hot packed-mask rows. (512,4) caps the allocator at 64 VGPRs; v12b's
// live set (~66: acc 16 + s 16 + mw 16 + qf 8 + temps) slightly exceeds it
// -> mild spill. Freeing ~15 VGPRs brings the live set under the cap.
// Same addresses, same values; extra load issue slots are free (<25% pipe
// utilization) and latency hides under 2-block interleave.
__global__ __launch_bounds__(512, 4) void qkv_attn_kernel(
        const ushort_t* __restrict__ hb,    // [16384][128] bf16
        const ushort_t* __restrict__ WqkvT, // layer slice [384][128] bf16 B^T
        const uint_t* __restrict__ pm,      // packed mask
        ushort_t* __restrict__ Aout) {      // [16384][128] bf16
    __shared__ __align__(16) ushort_t sm[34944];   // 69.9 KB -> 2 blocks/CU
    ushort_t* KF  = sm;            // 8192u  (16 tiles * 512)
    ushort_t* Vt  = sm + 8192;     // 8320u  [16][520]
    ushort_t* Qs  = sm + 16512;    // 8192u  [512][16]  (phase 1 out; freed after qf load)
    ushort_t* Ws  = sm + 24704;    // 6144u  [48][128]  (phase 1 weights)
    ushort_t* PsA = sm + 16512;    // 9216u  (phase 2; aliases Qs + Ws head)
    ushort_t* PsB = sm + 25728;    // 9216u  (aliases Ws tail)

    const int tid = threadIdx.x;
    const int w = tid >> 6, L = tid & 63;
    const int lr = L & 15, lq = L >> 4;
    const int lane31 = L & 31, lhalf = L >> 5;
    const int bx = blockIdx.x;
    const int u = ((bx & 7) << 5) | (bx >> 3);   // XCD-major relabel (T1)
    const int b = u >> 3, h = u & 7;

    for (int i = tid; i < 768; i += 512) {
        const int row = i >> 4, cg = i & 15;
        const int proj = row >> 4, kk = row & 15;
        gload16(WqkvT + (size_t)(proj * 128 + h * 16 + kk) * 128 + cg * 8, &Ws[i * 8]);
    }
    __syncthreads();

    const ushort_t* Ab = hb + (size_t)b * 512 * 128;
    for (int mc = 0; mc < 4; mc++) {
        f32x4 acc[3];
#pragma unroll
        for (int j = 0; j < 3; j++) acc[j] = (f32x4){0.f, 0.f, 0.f, 0.f};
#pragma unroll
        for (int k0 = 0; k0 < 128; k0 += 32) {
            short8 af = *(const short8*)(Ab + (size_t)(mc * 128 + w * 16 + lr) * 128 + k0 + lq * 8);
#pragma unroll
            for (int j = 0; j < 3; j++) {
                short8 bf = *(const short8*)&Ws[(j * 16 + lr) * 128 + k0 + lq * 8];
                acc[j] = __builtin_amdgcn_mfma_f32_16x16x32_bf16(af, bf, acc[j], 0, 0, 0);
            }
        }
        const int rbase = mc * 128 + w * 16 + lq * 4;
#pragma unroll
        for (int r = 0; r < 4; r++) {
            const int key = rbase + r;
            KF[(key >> 5) * 512 + ((lr >> 3) * 32 + (key & 31)) * 8 + (lr & 7)] = f2bf(acc[1][r]);
            Vt[lr * 520 + key] = f2bf(acc[2][r]);
            Qs[(key) * 16 + lr] = f2bf(acc[0][r] * QSCALE);
        }
    }
    __syncthreads();   // KF/Vt/Qs complete

    // pull BOTH q-fragments into registers, then free Qs for Ps reuse
    const short8 qf0 = *(const short8*)&Qs[(w * 32 + lane31) * 16 + lhalf * 8];
    const short8 qf1 = *(const short8*)&Qs[(256 + w * 32 + lane31) * 16 + lhalf * 8];
    __syncthreads();   // qf reads done; Qs/Ws regions now writable as PsA/PsB

    const f32x16 zero16 = (f32x16)(0.f);
    short8 vone;
#pragma unroll
    for (int i = 0; i < 8; i++) vone[i] = (short)0x3F80;   // bf16 1.0

// score-compute for tile T into PS: QK-MFMA, exp/mask, pack, ds_write
// mask word loaded per-step from L2-hot pmr2 (frees the 16-VGPR mw array)
#define CS_STEP(T_IDX, PS) do {                                                     \
    short8 kf = *(const short8*)&KF[(T_IDX) * 512 + L * 8];                         \
    f32x16 s = __builtin_amdgcn_mfma_f32_32x32x16_bf16(kf, qf, zero16, 0, 0, 0);    \
    const uint_t word = pmr2[(T_IDX)];                                              \
    _Pragma("unroll")                                                               \
    for (int r = 0; r < 16; r++) {                                                  \
        const int keyl = (r & 3) + 8 * (r >> 2) + 4 * lhalf;                        \
        const float e = exp2fast(s[r]);                                             \
        s[r] = (word & (1u << keyl)) ? e : 0.f;                                     \
    }                                                                               \
    _Pragma("unroll")                                                               \
    for (int g = 0; g < 4; g++) {                                                   \
        const uint_t lo = pack2bf_tr(s[g * 4 + 0], s[g * 4 + 1]);                   \
        const uint_t hi = pack2bf_tr(s[g * 4 + 2], s[g * 4 + 3]);                   \
        *(uint2*)&(PS)[w * 1152 + lane31 * 36 + g * 8 + 4 * lhalf] = make_uint2(lo, hi); \
    }                                                                               \
} while (0)

// PV accumulate for tile T from PS (reads + 4 MFMAs)
#define PV_STEP(T_IDX, PS) do {                                                     \
    short8 vb = *(const short8*)&Vt[lr * 520 + (T_IDX) * 32 + lq * 8];              \
    short8 pa0 = *(const short8*)&(PS)[w * 1152 + lr * 36 + lq * 8];                \
    short8 pa1 = *(const short8*)&(PS)[w * 1152 + (16 + lr) * 36 + lq * 8];         \
    oacc0 = __builtin_amdgcn_mfma_f32_16x16x32_bf16(pa0, vb, oacc0, 0, 0, 0);       \
    oacc1 = __builtin_amdgcn_mfma_f32_16x16x32_bf16(pa1, vb, oacc1, 0, 0, 0);       \
    lacc0 = __builtin_amdgcn_mfma_f32_16x16x32_bf16(pa0, vone, lacc0, 0, 0, 0);     \
    lacc1 = __builtin_amdgcn_mfma_f32_16x16x32_bf16(pa1, vone, lacc1, 0, 0, 0);     \
} while (0)

// pipelined body: PV(T-1) ds_reads issued BEFORE CS(T)'s ds_writes
#define PIPE_STEP(T_IDX, PSCUR, PSPREV) do {                                        \
    short8 kf = *(const short8*)&KF[(T_IDX) * 512 + L * 8];                         \
    f32x16 s = __builtin_amdgcn_mfma_f32_32x32x16_bf16(kf, qf, zero16, 0, 0, 0);    \
    PV_STEP((T_IDX) - 1, PSPREV);                                                   \
    const uint_t word = pmr2[(T_IDX)];                                              \
    _Pragma("unroll")                                                               \
    for (int r = 0; r < 16; r++) {                                                  \
        const int keyl = (r & 3) + 8 * (r >> 2) + 4 * lhalf;                        \
        const float e = exp2fast(s[r]);                                             \
        s[r] = (word & (1u << keyl)) ? e : 0.f;                                     \
    }                                                                               \
    _Pragma("unroll")                                                               \
    for (int g = 0; g < 4; g++) {                                                   \
        const uint_t lo = pack2bf_tr(s[g * 4 + 0], s[g * 4 + 1]);                   \
        const uint_t hi = pack2bf_tr(s[g * 4 + 2], s[g * 4 + 3]);                   \
        *(uint2*)&(PSCUR)[w * 1152 + lane31 * 36 + g * 8 + 4 * lhalf] = make_uint2(lo, hi); \
    }                                                                               \
} while (0)

    for (int qloop = 0; qloop < 2; ++qloop) {
        const int q0g = qloop * 256 + w * 32;
        const short8 qf = qloop ? qf1 : qf0;
        const uint_t* __restrict__ pmr2 = pm + (size_t)(b * 512 + q0g + lane31) * 16;

        f32x4 oacc0 = (f32x4){0.f, 0.f, 0.f, 0.f};
        f32x4 oacc1 = (f32x4){0.f, 0.f, 0.f, 0.f};
        f32x4 lacc0 = (f32x4){0.f, 0.f, 0.f, 0.f};
        f32x4 lacc1 = (f32x4){0.f, 0.f, 0.f, 0.f};

        CS_STEP(0, PsA);
#pragma unroll
        for (int tp = 0; tp < 7; tp++) {
            PIPE_STEP(2 * tp + 1, PsB, PsA);
            PIPE_STEP(2 * tp + 2, PsA, PsB);
        }
        PIPE_STEP(15, PsB, PsA);
        PV_STEP(15, PsB);

#pragma unroll
        for (int qa = 0; qa < 2; qa++) {
            const f32x4 oa = qa ? oacc1 : oacc0;
            const f32x4 la = qa ? lacc1 : lacc0;
#pragma unroll
            for (int rr = 0; rr < 4; rr++) {
                const int qloc = qa * 16 + lq * 4 + rr;
                Aout[(size_t)(b * 512 + q0g + qloc) * 128 + h * 16 + lr] = f2bf(oa[rr] / la[rr]);
            }
        }
    }
#undef CS_STEP
#undef PV_STEP
#undef PIPE_STEP
}

// ---------------- fused layer tail v4: ping-pong double-buffered staging ----------------
// (exact R0/R3 config — measured-best)
__global__ __launch_bounds__(256, 2) void tail_kernel(
        const ushort_t* __restrict__ A,     // a16 [16384][128]
        const ushort_t* __restrict__ WoT,   // [128 n][128 k]
        const ushort_t* __restrict__ W1T,   // [512 n][128 k]
        const ushort_t* __restrict__ W2T,   // [128 n][512 k]
        const float* __restrict__ b1,
        const float* __restrict__ b2,
        float* __restrict__ hf, ushort_t* __restrict__ hb,
        float* __restrict__ pbsum, int accum) {
    __shared__ __align__(16) ushort_t sm[39424];   // 78.85 KB -> 2 blocks/CU
    ushort_t* AsA = sm;            // 1024  (32x32 chunk)
    ushort_t* AsB = sm + 1024;     // 1024
    ushort_t* BsA = sm + 2048;     // 8192  (up to 256x32 chunk)
    ushort_t* BsB = sm + 10240;    // 8192
    ushort_t* C1b = sm + 18432;    // 4352  (32x136)
    ushort_t* T   = sm + 22784;    // 16640 (32x520)

    const int tid = threadIdx.x;
    const int w = tid >> 6, l = tid & 63;
    const int lr = l & 15, lq = l >> 4;
    const int srow = (l >> 2);
    const int scol = (l & 3) * 8;
    const int m0 = blockIdx.x * 32;

    // ================ phase A: C1 = a16 @ WoT^T + h ================
    f32x4 c1a[2][2];
#pragma unroll
    for (int i = 0; i < 2; i++)
#pragma unroll
        for (int j = 0; j < 2; j++) c1a[i][j] = (f32x4){0.f, 0.f, 0.f, 0.f};
    // prologue: stage k0=0
    if (w < 2)
        gload16(A + (size_t)(m0 + w * 16 + srow) * 128 + scol, &AsA[(w * 16 + srow) * 32 + scol]);
#pragma unroll
    for (int it = 0; it < 2; it++)
        gload16(WoT + (size_t)(it * 64 + w * 16 + srow) * 128 + scol, &BsA[(it * 64 + w * 16 + srow) * 32 + scol]);
#pragma unroll
    for (int k0 = 0; k0 < 128; k0 += 32) {
        ushort_t* Ac = (k0 & 32) ? AsB : AsA;
        ushort_t* Bc = (k0 & 32) ? BsB : BsA;
        ushort_t* An = (k0 & 32) ? AsA : AsB;
        ushort_t* Bn = (k0 & 32) ? BsA : BsB;
        __syncthreads();   // chunk k0 staged; prior reads of An/Bn done
        if (k0 + 32 < 128) {
            if (w < 2)
                gload16(A + (size_t)(m0 + w * 16 + srow) * 128 + k0 + 32 + scol,
                        &An[(w * 16 + srow) * 32 + scol]);
#pragma unroll
            for (int it = 0; it < 2; it++)
                gload16(WoT + (size_t)(it * 64 + w * 16 + srow) * 128 + k0 + 32 + scol,
                        &Bn[(it * 64 + w * 16 + srow) * 32 + scol]);
        }
        short8 af[2], bfr[2];
#pragma unroll
        for (int i = 0; i < 2; i++) af[i] = *(const short8*)&Ac[(i * 16 + lr) * 32 + lq * 8];
#pragma unroll
        for (int j = 0; j < 2; j++) bfr[j] = *(const short8*)&Bc[(w * 32 + j * 16 + lr) * 32 + lq * 8];
#pragma unroll
        for (int i = 0; i < 2; i++)
#pragma unroll
            for (int j = 0; j < 2; j++)
                c1a[i][j] = __builtin_amdgcn_mfma_f32_16x16x32_bf16(af[i], bfr[j], c1a[i][j], 0, 0, 0);
    }
    // epilogue A: + residual h (fp32 regs + bf16 LDS)
    float c1[2][2][4];
#pragma unroll
    for (int i = 0; i < 2; i++)
#pragma unroll
        for (int r = 0; r < 4; r++) {
            const int row = i * 16 + lq * 4 + r;
#pragma unroll
            for (int j = 0; j < 2; j++) {
                const int n = w * 32 + j * 16 + lr;
                const float v = c1a[i][j][r] + hf[(size_t)(m0 + row) * 128 + n];
                c1[i][j][r] = v;
                C1b[row * 136 + n] = f2bf(v);
            }
        }

    // ================ phase B: T = relu(C1 @ W1T^T + b1), 2 n-halves x 4 k-chunks ================
#pragma unroll
    for (int it = 0; it < 4; it++)
        gload16(W1T + (size_t)(it * 64 + w * 16 + srow) * 128 + scol, &BsA[(it * 64 + w * 16 + srow) * 32 + scol]);
#pragma unroll
    for (int nc = 0; nc < 2; nc++) {
        f32x4 ta[2][4];
#pragma unroll
        for (int i = 0; i < 2; i++)
#pragma unroll
            for (int j = 0; j < 4; j++) ta[i][j] = (f32x4){0.f, 0.f, 0.f, 0.f};
#pragma unroll
        for (int k0i = 0; k0i < 4; k0i++) {
            const int c = nc * 4 + k0i;
            ushort_t* Bc = (c & 1) ? BsB : BsA;
            ushort_t* Bn = (c & 1) ? BsA : BsB;
            __syncthreads();   // chunk c staged; also orders C1b writes (first iter)
            if (c + 1 < 8) {
                const int nc2 = (c + 1) >> 2, k02 = ((c + 1) & 3) * 32;
#pragma unroll
                for (int it = 0; it < 4; it++)
                    gload16(W1T + (size_t)(nc2 * 256 + it * 64 + w * 16 + srow) * 128 + k02 + scol,
                            &Bn[(it * 64 + w * 16 + srow) * 32 + scol]);
            }
            short8 af[2], bfr[4];
#pragma unroll
            for (int i = 0; i < 2; i++)
                af[i] = *(const short8*)&C1b[(i * 16 + lr) * 136 + k0i * 32 + lq * 8];
#pragma unroll
            for (int j = 0; j < 4; j++)
                bfr[j] = *(const short8*)&Bc[(w * 64 + j * 16 + lr) * 32 + lq * 8];
#pragma unroll
            for (int i = 0; i < 2; i++)
#pragma unroll
                for (int j = 0; j < 4; j++)
                    ta[i][j] = __builtin_amdgcn_mfma_f32_16x16x32_bf16(af[i], bfr[j], ta[i][j], 0, 0, 0);
        }
        // epilogue nc: +b1, relu -> T (distinct region; staging for next chunk flies concurrently)
#pragma unroll
        for (int j = 0; j < 4; j++) {
            const int n = nc * 256 + w * 64 + j * 16 + lr;
            const float bv = b1[n];
#pragma unroll
            for (int i = 0; i < 2; i++)
#pragma unroll
                for (int r = 0; r < 4; r++) {
                    const int row = i * 16 + lq * 4 + r;
                    T[row * 520 + n] = f2bf(fmaxf(ta[i][j][r] + bv, 0.f));
                }
        }
    }

    // ================ phase C: h' = C1 + T @ W2T^T + b2, 16 k-chunks ================
#pragma unroll
    for (int it = 0; it < 2; it++)
        gload16(W2T + (size_t)(it * 64 + w * 16 + srow) * 512 + scol, &BsA[(it * 64 + w * 16 + srow) * 32 + scol]);
    f32x4 oa[2][2];
#pragma unroll
    for (int i = 0; i < 2; i++)
#pragma unroll
        for (int j = 0; j < 2; j++) oa[i][j] = (f32x4){0.f, 0.f, 0.f, 0.f};
#pragma unroll
    for (int k0 = 0; k0 < 512; k0 += 32) {
        ushort_t* Bc = ((k0 >> 5) & 1) ? BsB : BsA;
        ushort_t* Bn = ((k0 >> 5) & 1) ? BsA : BsB;
        __syncthreads();   // chunk staged; T writes ordered (first iter)
        if (k0 + 32 < 512) {
#pragma unroll
            for (int it = 0; it < 2; it++)
                gload16(W2T + (size_t)(it * 64 + w * 16 + srow) * 512 + k0 + 32 + scol,
                        &Bn[(it * 64 + w * 16 + srow) * 32 + scol]);
        }
        short8 af[2], bfr[2];
#pragma unroll
        for (int i = 0; i < 2; i++)
            af[i] = *(const short8*)&T[(i * 16 + lr) * 520 + k0 + lq * 8];
#pragma unroll
        for (int j = 0; j < 2; j++)
            bfr[j] = *(const short8*)&Bc[(w * 32 + j * 16 + lr) * 32 + lq * 8];
#pragma unroll
        for (int i = 0; i < 2; i++)
#pragma unroll
            for (int j = 0; j < 2; j++)
                oa[i][j] = __builtin_amdgcn_mfma_f32_16x16x32_bf16(af[i], bfr[j], oa[i][j], 0, 0, 0);
    }
    // epilogue C: + b2 + C1 -> global fp32 + bf16 (+ pooled-sum atomics on last layer)
#pragma unroll
    for (int j = 0; j < 2; j++) {
        const int n = w * 32 + j * 16 + lr;
        const float bv = b2[n];
        float psum = 0.f;
#pragma unroll
        for (int i = 0; i < 2; i++)
#pragma unroll
            for (int r = 0; r < 4; r++) {
                const int row = i * 16 + lq * 4 + r;
                const float v = oa[i][j][r] + bv + c1[i][j][r];
                psum += v;
                hf[(size_t)(m0 + row) * 128 + n] = v;
                hb[(size_t)(m0 + row) * 128 + n] = f2bf(v);
            }
        if (accum) {
            psum += __shfl_xor(psum, 16);
            psum += __shfl_xor(psum, 32);
            if (lq == 0) atomicAdd(&pbsum[(m0 >> 9) * 128 + n], psum);
        }
    }
}

// ------------- readout: 512 blocks, 32 rows each (unchanged) -------------
__global__ __launch_bounds__(256) void readout_kernel(const float* __restrict__ h,
                                                      const float* __restrict__ pbsum,
                                                      const float* __restrict__ Wp,
                                                      const float* __restrict__ Wr,
                                                      const float* __restrict__ br,
                                                      float* __restrict__ out) {
    const int u = blockIdx.x;
    const int b = u >> 4;
    const int m0 = u * 32;
    const int t = threadIdx.x;
    __shared__ float pooled[128];
    __shared__ float rp[128];
    __shared__ float pb3[3];
    if (t < 128) pooled[t] = pbsum[b * 128 + t] * (1.0f / 512.0f);
    __syncthreads();
    if (t < 128) {
        float a = 0.f;
        for (int dd = 0; dd < 128; dd++) a += pooled[dd] * Wp[dd * 128 + t];
        rp[t] = fmaxf(a, 0.f);
    }
    __syncthreads();
    if (t < OUT_DIM) {
        float a = br[t];
        for (int j = 0; j < 128; j++) a += rp[j] * Wr[j * 3 + t];
        pb3[t] = a;
    }
    __syncthreads();
    const int j = t & 7;
    const int row = m0 + (t >> 3);
    const float* hr = h + (size_t)row * 128 + j * 16;
    float a0 = 0.f, a1 = 0.f, a2o = 0.f;
#pragma unroll
    for (int dd = 0; dd < 16; dd++) {
        const float v = fmaxf(hr[dd], 0.f);
        const float* wr = Wr + (size_t)(128 + j * 16 + dd) * 3;
        a0 += v * wr[0]; a1 += v * wr[1]; a2o += v * wr[2];
    }
#pragma unroll
    for (int off = 4; off; off >>= 1) {
        a0 += __shfl_down(a0, off, 8);
        a1 += __shfl_down(a1, off, 8);
        a2o += __shfl_down(a2o, off, 8);
    }
    if (j == 0) {
        out[(size_t)row * 3 + 0] = a0 + pb3[0];
        out[(size_t)row * 3 + 1] = a1 + pb3[1];
        out[(size_t)row * 3 + 2] = a2o + pb3[2];
    }
}

extern "C" void kernel_launch(void* const* d_in, const int* in_sizes, int n_in,
                              void* d_out, int out_size, void* d_ws, size_t ws_size,
                              hipStream_t stream) {
    const float* x    = (const float*)d_in[0];
    const int*   mask = (const int*)d_in[1];
    const float* We   = (const float*)d_in[2];
    const float* Wq   = (const float*)d_in[3];
    const float* Wk   = (const float*)d_in[4];
    const float* Wv   = (const float*)d_in[5];
    const float* Wout = (const float*)d_in[6];
    const float* Wff1 = (const float*)d_in[7];
    const float* bff1 = (const float*)d_in[8];
    const float* Wff2 = (const float*)d_in[9];
    const float* bff2 = (const float*)d_in[10];
    const float* Wp   = (const float*)d_in[11];
    const float* Wr   = (const float*)d_in[12];
    const float* br   = (const float*)d_in[13];
    float* out = (float*)d_out;

    char* ws = (char*)d_ws;
    unsigned long long* pm64 = (unsigned long long*)(ws + 0);        // 1 MiB
    const uint_t* pm32       = (const uint_t*)(ws + 0);
    ushort_t* wqkvT = (ushort_t*)(ws + 1048576);
    ushort_t* woutT = (ushort_t*)(ws + 1343488);
    ushort_t* wff1T = (ushort_t*)(ws + 1441792);
    ushort_t* wff2T = (ushort_t*)(ws + 1835008);
    float*    pbsum = (float*)(ws + 2228224);                        // 16 KiB pooled sums
    float*    hbuf  = (float*)(ws + 4194304);                        // 8 MiB fp32 residual
    ushort_t* hb16  = (ushort_t*)(ws + 12582912);                    // 4 MiB bf16 mirror
    ushort_t* a16   = (ushort_t*)(ws + 41943040);                    // 4 MiB attn out

    preproc_kernel<<<PM_BLK + RQ_BLK + TW_BLK + T1_BLK + T2_BLK + PB_BLK + EM_BLK, 256, 0, stream>>>(
        mask, pm64, Wq, Wk, Wv, wqkvT, Wout, woutT, Wff1, wff1T, Wff2, wff2T,
        pbsum, x, We, hbuf, hb16);

    for (int l = 0; l < L_LAYERS; l++) {
        qkv_attn_kernel<<<256, 512, 0, stream>>>(
            hb16, wqkvT + (size_t)l * 384 * 128, pm32, a16);
        tail_kernel<<<M_ROWS / 32, 256, 0, stream>>>(
            a16, woutT + (size_t)l * 128 * 128, wff1T + (size_t)l * 512 * 128,
            wff2T + (size_t)l * 128 * 512, bff1 + l * 512, bff2 + l * 128,
            hbuf, hb16, pbsum, (l == L_LAYERS - 1) ? 1 : 0);
    }

    readout_kernel<<<512, 256, 0, stream>>>(hbuf, pbsum, Wp, Wr, br, out);
}